// Round 5
// baseline (6876.523 us; speedup 1.0000x reference)
//
#include <hip/hip_runtime.h>
#include <hip/hip_bf16.h>

#define N_ATM 131072
#define N_BND 1048576
#define N_ANG 2097152
#define N_GRAPHS 256
#define PI_F 3.14159265358979323846f

#define FMAIN 256
#define FEXT 64
#define FWIN (FMAIN + FEXT)   // 320 slots per block window
#define NTHR 320              // fused kernel block size: one thread per window slot

typedef __hip_bfloat16 bf16;

__device__ __forceinline__ int clampi(int v, int lo, int hi) {
    return v < lo ? lo : (v > hi ? hi : v);
}
__device__ __forceinline__ float b2f(bf16 v) { return __bfloat162float(v); }
__device__ __forceinline__ float sigmoidf_(float x) { return 1.0f / (1.0f + __expf(-x)); }
__device__ __forceinline__ float siluf_(float x) { return x / (1.0f + __expf(-x)); }

__device__ __forceinline__ float loadF(const void* p, long long i, int isbf) {
    return isbf ? b2f(((const bf16*)p)[i]) : ((const float*)p)[i];
}
__device__ __forceinline__ float bfbits2f(unsigned lo16) {
    union { unsigned u; float f; } c; c.u = lo16 << 16; return c.f;
}
__device__ __forceinline__ unsigned f2bfbits(float f) {
    union { float f; unsigned u; } c; c.f = f;
    unsigned u = c.u + 0x7FFFu + ((c.u >> 16) & 1u);  // RNE
    return u >> 16;
}

// ---- 16-wide row IO ----
__device__ __forceinline__ void load16f(const float* p, float* r) {
    const float4* q = (const float4*)p;
#pragma unroll
    for (int i = 0; i < 4; i++) { float4 v = q[i]; r[4*i]=v.x; r[4*i+1]=v.y; r[4*i+2]=v.z; r[4*i+3]=v.w; }
}
__device__ __forceinline__ void store16f(float* p, const float* r) {
    float4* q = (float4*)p;
#pragma unroll
    for (int i = 0; i < 4; i++) q[i] = make_float4(r[4*i], r[4*i+1], r[4*i+2], r[4*i+3]);
}
__device__ __forceinline__ void load16b(const bf16* p, float* r) {
    uint4 a = ((const uint4*)p)[0];
    uint4 b = ((const uint4*)p)[1];
    unsigned w[8] = {a.x, a.y, a.z, a.w, b.x, b.y, b.z, b.w};
#pragma unroll
    for (int i = 0; i < 8; i++) {
        r[2*i] = bfbits2f(w[i] & 0xFFFFu);
        union { unsigned u; float f; } c; c.u = w[i] & 0xFFFF0000u;
        r[2*i+1] = c.f;
    }
}
__device__ __forceinline__ void store16b(bf16* p, const float* r) {
    unsigned w[8];
#pragma unroll
    for (int i = 0; i < 8; i++)
        w[i] = f2bfbits(r[2*i]) | (f2bfbits(r[2*i+1]) << 16);
    ((uint4*)p)[0] = make_uint4(w[0], w[1], w[2], w[3]);
    ((uint4*)p)[1] = make_uint4(w[4], w[5], w[6], w[7]);
}

template <typename TX>
__device__ __forceinline__ void loadRow(const TX* p, float* r);
template <> __device__ __forceinline__ void loadRow<float>(const float* p, float* r) { load16f(p, r); }
template <> __device__ __forceinline__ void loadRow<bf16>(const bf16* p, float* r) { load16b(p, r); }
template <typename TX>
__device__ __forceinline__ void storeRow(TX* p, const float* r);
template <> __device__ __forceinline__ void storeRow<float>(float* p, const float* r) { store16f(p, r); }
template <> __device__ __forceinline__ void storeRow<bf16>(bf16* p, const float* r) { store16b(p, r); }

// ---------- utility ----------
__global__ void __launch_bounds__(256) k_zero_int(int* __restrict__ p, int n) {
    int i = blockIdx.x * 256 + threadIdx.x;
    if (i < n) p[i] = 0;
}

// flags[0]=1 if float tensors are bf16; flags[1]=1 if mask is byte-bools
__global__ void __launch_bounds__(256) k_detect(const void* lng, const unsigned* __restrict__ mask,
                                                int* flags) {
    int i = blockIdx.x * 256 + threadIdx.x;
    if (i == 0) flags[0] = (*(const unsigned*)lng == 0x3F803F80u) ? 1 : 0;
    int bad = 0;
    for (int j = i; j < 512 * 1024; j += 512 * 256)
        if (mask[j] > 1u) bad = 1;
    if (bad) atomicOr(&flags[1], 1);
}

__global__ void k_cvt_any(const void* __restrict__ src, float* __restrict__ dst, int n,
                          const int* __restrict__ flags) {
    int i = blockIdx.x * blockDim.x + threadIdx.x;
    if (i < n) dst[i] = loadF(src, i, flags[0]);
}

// ---------- CSR build ----------
__global__ void __launch_bounds__(256) k_count(const int* __restrict__ dst, int* __restrict__ cnt,
                                               int E, int n) {
    int i = blockIdx.x * 256 + threadIdx.x;
    if (i >= E) return;
    atomicAdd(&cnt[clampi(dst[i], 0, n - 1)], 1);
}
__global__ void __launch_bounds__(256) k_scan_local(const int* __restrict__ cnt, int* __restrict__ ofs,
                                                    int* __restrict__ bsum, int n) {
    __shared__ int s[256];
    int t = threadIdx.x, i = blockIdx.x * 256 + t;
    int v = (i < n) ? cnt[i] : 0;
    s[t] = v; __syncthreads();
    for (int o = 1; o < 256; o <<= 1) {
        int add = (t >= o) ? s[t - o] : 0;
        __syncthreads();
        s[t] += add;
        __syncthreads();
    }
    if (i < n) ofs[i] = s[t] - v;
    if (t == 255) bsum[blockIdx.x] = s[255];
}
__global__ void __launch_bounds__(256) k_scan_bsum(int* __restrict__ bsum, int nb) {
    __shared__ int s[256];
    __shared__ int run;
    int t = threadIdx.x;
    if (t == 0) run = 0;
    __syncthreads();
    for (int base = 0; base < nb; base += 256) {
        int i = base + t;
        int v = (i < nb) ? bsum[i] : 0;
        s[t] = v; __syncthreads();
        for (int o = 1; o < 256; o <<= 1) {
            int add = (t >= o) ? s[t - o] : 0;
            __syncthreads();
            s[t] += add;
            __syncthreads();
        }
        if (i < nb) bsum[i] = run + s[t] - v;
        __syncthreads();
        if (t == 0) run += s[255];
        __syncthreads();
    }
}
// finalizes ofs (adds block sums), copies cursor, writes sentinel ofs[n]=total
__global__ void __launch_bounds__(256) k_scan_add2(int* __restrict__ ofs, const int* __restrict__ bsum,
                                                   int* __restrict__ cursor, int n, int total) {
    int i = blockIdx.x * 256 + threadIdx.x;
    if (i < n) { int v = ofs[i] + bsum[blockIdx.x]; ofs[i] = v; cursor[i] = v; }
    if (i == 0) ofs[n] = total;
}
// line graph: permuted src + original->slot map (for angle encoder)
__global__ void __launch_bounds__(256) k_scatter_line2(
    const int* __restrict__ src, const int* __restrict__ dst, int* __restrict__ cur,
    int* __restrict__ srcP, int* __restrict__ pos, int E, int n)
{
    int i = blockIdx.x * 256 + threadIdx.x;
    if (i >= E) return;
    int d = clampi(dst[i], 0, n - 1);
    int s = clampi(src[i], 0, n - 1);
    int p = clampi(atomicAdd(&cur[d], 1), 0, E - 1);
    srcP[p] = s; pos[i] = p;
}
// atom graph: permuted src + original bond id per slot
__global__ void __launch_bounds__(256) k_scatter_atom2(
    const int* __restrict__ src, const int* __restrict__ dst, int* __restrict__ cur,
    int* __restrict__ srcP, int* __restrict__ eidP, int E, int n, int ns)
{
    int i = blockIdx.x * 256 + threadIdx.x;
    if (i >= E) return;
    int d = clampi(dst[i], 0, n - 1);
    int s = clampi(src[i], 0, ns - 1);
    int p = clampi(atomicAdd(&cur[d], 1), 0, E - 1);
    srcP[p] = s; eidP[p] = i;
}
// per-block-boundary node ranges (CSR static across rounds -> compute once)
// owner[b] = last d with ofs[d] <= b*FMAIN ; first[b] = first d with ofs[d] >= b*FMAIN
__global__ void __launch_bounds__(256) k_blkrange(const int* __restrict__ ofs, int N, int nbp1,
                                                  int* __restrict__ owner, int* __restrict__ first) {
    int b = blockIdx.x * 256 + threadIdx.x;
    if (b >= nbp1) return;
    int B0 = b * FMAIN;
    int lo = 0, hi = N;
    while (lo < hi) { int m = (lo + hi) >> 1; if (ofs[m] < B0) lo = m + 1; else hi = m; }
    first[b] = lo;
    lo = 0; hi = N + 1;
    while (lo < hi) { int m = (lo + hi) >> 1; if (ofs[m] <= B0) lo = m + 1; else hi = m; }
    owner[b] = (lo - 1) < 0 ? 0 : (lo - 1);
}

// ---------- encoders ----------
__global__ void __launch_bounds__(256) k_enc_atm(
    const int* __restrict__ sp_in,
    const void* W1, const void* b1, const void* W2, const void* b2,
    const void* g, const void* be, const int* __restrict__ flags,
    float* __restrict__ out)
{
    __shared__ float sW1[256], sW2[256], sb1[16], sb2[16], sg[16], sbe[16];
    int t = threadIdx.x, isbf = flags[0];
    sW1[t] = loadF(W1, t, isbf); sW2[t] = loadF(W2, t, isbf);
    if (t < 16) { sb1[t]=loadF(b1,t,isbf); sb2[t]=loadF(b2,t,isbf); sg[t]=loadF(g,t,isbf); sbe[t]=loadF(be,t,isbf); }
    __syncthreads();
    int i = blockIdx.x * 256 + t;
    if (i >= N_ATM) return;
    int sp = clampi(sp_in[i], 0, 15);
    float h[16];
#pragma unroll
    for (int j = 0; j < 16; j++) h[j] = siluf_(sW1[sp * 16 + j] + sb1[j]);
    float o[16]; float mu = 0.f;
#pragma unroll
    for (int j = 0; j < 16; j++) {
        float a = sb2[j];
#pragma unroll
        for (int k = 0; k < 16; k++) a += h[k] * sW2[k * 16 + j];
        o[j] = a; mu += a;
    }
    mu *= (1.f / 16.f);
    float var = 0.f;
#pragma unroll
    for (int j = 0; j < 16; j++) { float d = o[j] - mu; var += d * d; }
    var *= (1.f / 16.f);
    float r = rsqrtf(var + 1e-5f);
    float ov[16];
#pragma unroll
    for (int j = 0; j < 16; j++) ov[j] = (o[j] - mu) * r * sg[j] + sbe[j];
    store16f(out + (long long)i * 16, ov);
}

__global__ void __launch_bounds__(256) k_enc_bnd(
    const void* __restrict__ xb,
    const void* W1, const void* b1, const void* W2, const void* b2,
    const void* g, const void* be, const int* __restrict__ flags,
    bf16* __restrict__ out)
{
    __shared__ float sW1[256], sW2[256], sb1[16], sb2[16], sg[16], sbe[16];
    int t = threadIdx.x, isbf = flags[0];
    sW1[t] = loadF(W1, 256 + t, isbf); sW2[t] = loadF(W2, 256 + t, isbf);
    if (t < 16) { sb1[t]=loadF(b1,16+t,isbf); sb2[t]=loadF(b2,16+t,isbf); sg[t]=loadF(g,16+t,isbf); sbe[t]=loadF(be,16+t,isbf); }
    __syncthreads();
    int i = blockIdx.x * 256 + t;
    if (i >= N_BND) return;
    float x = loadF(xb, i, isbf) + 1e-5f;
    const float c = 0.6324555320336759f; // sqrt(2/5)
    float inv = c / x;
    float feat[16];
#pragma unroll
    for (int k = 0; k < 16; k++) feat[k] = __sinf((float)(k + 1) * PI_F * x * 0.2f) * inv;
    float h[16];
#pragma unroll
    for (int j = 0; j < 16; j++) {
        float a = sb1[j];
#pragma unroll
        for (int k = 0; k < 16; k++) a += feat[k] * sW1[k * 16 + j];
        h[j] = siluf_(a);
    }
    float o[16]; float mu = 0.f;
#pragma unroll
    for (int j = 0; j < 16; j++) {
        float a = sb2[j];
#pragma unroll
        for (int k = 0; k < 16; k++) a += h[k] * sW2[k * 16 + j];
        o[j] = a; mu += a;
    }
    mu *= (1.f / 16.f);
    float var = 0.f;
#pragma unroll
    for (int j = 0; j < 16; j++) { float d = o[j] - mu; var += d * d; }
    var *= (1.f / 16.f);
    float r = rsqrtf(var + 1e-5f);
    float ov[16];
#pragma unroll
    for (int j = 0; j < 16; j++) ov[j] = (o[j] - mu) * r * sg[j] + sbe[j];
    store16b(out + (long long)i * 16, ov);
}

// angle encoder: writes row to CSR slot pos[i]
__global__ void __launch_bounds__(256) k_enc_ang(
    const void* __restrict__ xa, const void* __restrict__ mask,
    const void* W1, const void* b1, const void* W2, const void* b2,
    const void* g, const void* be, const int* __restrict__ flags,
    const int* __restrict__ pos, bf16* __restrict__ out)
{
    __shared__ float sW1[512], sW2[512], sb1[32], sb2[32], sg[32], sbe[32];
    int t = threadIdx.x, isbf = flags[0], mbyte = flags[1];
    for (int i = t; i < 512; i += 256) { sW1[i] = loadF(W1, 512 + i, isbf); sW2[i] = loadF(W2, 512 + i, isbf); }
    if (t < 32) { sb1[t]=loadF(b1,32+t,isbf); sb2[t]=loadF(b2,32+t,isbf); sg[t]=loadF(g,32+t,isbf); sbe[t]=loadF(be,32+t,isbf); }
    __syncthreads();
    int i = blockIdx.x * 256 + t;
    if (i >= N_ANG) return;
    int m = mbyte ? (((const unsigned char*)mask)[i] != 0) : (((const int*)mask)[i] != 0);
    float x = loadF(xa, i, isbf);
    float gam = m ? 2.3873241463784303f : 4.7746482927568605f;   // 15/(2pi) : 15/pi
    float c0  = m ? -PI_F : 0.0f;
    float dc  = m ? 0.41887902047863906f : 0.20943951023931953f; // 2pi/15 : pi/15
    int wo = m * 256, vo = m * 16;
    float feat[16];
#pragma unroll
    for (int k = 0; k < 16; k++) {
        float d = gam * (x - (c0 + (float)k * dc));
        feat[k] = __expf(-d * d);
    }
    float h[16];
#pragma unroll
    for (int j = 0; j < 16; j++) {
        float a = sb1[vo + j];
#pragma unroll
        for (int k = 0; k < 16; k++) a += feat[k] * sW1[wo + k * 16 + j];
        h[j] = siluf_(a);
    }
    float o[16]; float mu = 0.f;
#pragma unroll
    for (int j = 0; j < 16; j++) {
        float a = sb2[vo + j];
#pragma unroll
        for (int k = 0; k < 16; k++) a += h[k] * sW2[wo + k * 16 + j];
        o[j] = a; mu += a;
    }
    mu *= (1.f / 16.f);
    float var = 0.f;
#pragma unroll
    for (int j = 0; j < 16; j++) { float d = o[j] - mu; var += d * d; }
    var *= (1.f / 16.f);
    float r = rsqrtf(var + 1e-5f);
    float ov[16];
#pragma unroll
    for (int j = 0; j < 16; j++) ov[j] = (o[j] - mu) * r * sg[vo + j] + sbe[vo + j];
    store16b(out + (long long)clampi(pos[i], 0, N_ANG - 1) * 16, ov);
}

// ---------- shared edge math (liveness-ordered) ----------
// Pass A: z = xs@W0 + xd@W1 + ev@W2 + b0 and mm = xs@W4 (combined k-loop; xs/xd die).
// Pass B: pack {sigma*mm, sigma} -> LDS immediately (mm dies).
// Pass C: eo = ev + silu(LN(z)*g+b) (ev, z die).
__device__ __forceinline__ void edge_core(
    const float* xs, const float* xd, const float* ev,
    const float* sW, const float* sB, const float* sLg, const float* sLb,
    float* eo, uint4* msLDS)
{
    float z[16], mm[16];
#pragma unroll
    for (int j = 0; j < 16; j++) { z[j] = sB[j]; mm[j] = 0.f; }
#pragma unroll
    for (int k = 0; k < 16; k++) {
        float a = xs[k], c = xd[k], q = ev[k];
#pragma unroll
        for (int j = 0; j < 16; j++) {
            z[j] += a * sW[k * 16 + j] + c * sW[256 + k * 16 + j] + q * sW[512 + k * 16 + j];
            mm[j] += a * sW[1024 + k * 16 + j];
        }
    }
    // pack (sigma*mm, sigma) straight to LDS; mm dies here
    {
        unsigned w0[4], w1[4];
#pragma unroll
        for (int i = 0; i < 8; i++) {
            float a0 = sigmoidf_(z[2*i]);
            float a1 = sigmoidf_(z[2*i+1]);
            w0[i & 3] = f2bfbits(a0 * mm[2*i]) | (f2bfbits(a1 * mm[2*i+1]) << 16);
            w1[i & 3] = f2bfbits(a0)           | (f2bfbits(a1) << 16);
            if ((i & 3) == 3) {
                msLDS[(i >> 2)]     = make_uint4(w0[0], w0[1], w0[2], w0[3]);
                msLDS[(i >> 2) + 2] = make_uint4(w1[0], w1[1], w1[2], w1[3]);
            }
        }
    }
    float mu = 0.f;
#pragma unroll
    for (int j = 0; j < 16; j++) mu += z[j];
    mu *= (1.f / 16.f);
    float var = 0.f;
#pragma unroll
    for (int j = 0; j < 16; j++) { float dd = z[j] - mu; var += dd * dd; }
    var *= (1.f / 16.f);
    float r = rsqrtf(var + 1e-5f);
#pragma unroll
    for (int j = 0; j < 16; j++)
        eo[j] = ev[j] + siluf_((z[j] - mu) * r * sLg[j] + sLb[j]);
}

// ---------- fused edge+node conv (one thread per window slot; NO loop, ONE call site) ----------
// Block b owns CSR slots [b*256, b*256+256); 320 threads cover main + <=64 extension
// slots (the straddler node's tail; no Eout write there - the owning block writes those
// rows). (msg,sigma) staged in LDS as 4x uint4 per slot, slot stride 5 uint4s (pad ->
// banks spread). LDS layout per slot: [0]=msg w0-3, [1]=msg w4-7, [2]=sig w0-3, [3]=sig w4-7.
// e is fully ping-ponged (Ein read-only) so extension reads never race another block's
// e_new writes.
// VIA_EID: e rows accessed through eid[] (atom graph: bonds stored in natural order).
// Node phase: all d with ofs[d] in [B0, B0+256); last block also absorbs trailing
// deg-0 nodes (num=den=0 -> matches reference).
// __launch_bounds__(NTHR, 1): min 1 wave/EU -> no heuristic VGPR cap (default for
// 5-wave workgroups is 4 waves/EU -> 128-reg cap -> aggregate scratch demotion, the
// R4 spill). HW launchability of 5 waves still bounds VGPR at 256; demand ~150-170.
template <typename TX, bool VIA_EID>
__global__ void __launch_bounds__(NTHR, 1) k_fused(
    const TX* __restrict__ X, TX* __restrict__ Xn,
    const bf16* __restrict__ Ein, bf16* __restrict__ Eout,
    const int* __restrict__ src, const int* __restrict__ eid,
    const int* __restrict__ ofs, const int* __restrict__ owner, const int* __restrict__ first,
    const float* __restrict__ W, const float* __restrict__ Bp, const float* __restrict__ L,
    int E, int N, int nb)
{
    __shared__ float sW[1280], sB[32], sLg[32], sLb[32];
    __shared__ uint4 sMS4[FWIN * 5];   // slot w -> sMS4[w*5 .. w*5+3], +1 pad
    __shared__ int sDst[FWIN];
    int t = threadIdx.x;
    int b = blockIdx.x;
    int B0 = b * FMAIN;
    for (int i = t; i < 1280; i += NTHR) sW[i] = W[i];
    if (t < 16) {
        sB[t] = Bp[t];        sB[16 + t] = Bp[16 + t];
        sLg[t] = L[32 + t];   sLb[t] = L[48 + t];       // edge LN
        sLg[16 + t] = L[t];   sLb[16 + t] = L[16 + t];  // node LN
    }
    int d0      = owner[b];
    int dNodeLo = first[b];
    int dhi     = first[b + 1];
    int dhiN    = (b == nb - 1) ? N : dhi;
    // fill slot -> dst map for the window
    for (int dd = d0 + t; dd < dhi; dd += NTHR) {
        int a = ofs[dd], e2 = ofs[dd + 1];
        int lo2 = a < B0 ? B0 : a;
        int hi2 = e2 > B0 + FWIN ? B0 + FWIN : e2;
        for (int p = lo2; p < hi2; p++) sDst[p - B0] = dd;
    }
    __syncthreads();
    // ---- edge phase: one slot per thread, single call site ----
    int eExt = ofs[clampi(dhi, 0, N)] - (B0 + FMAIN);
    eExt = eExt < 0 ? 0 : (eExt > FEXT ? FEXT : eExt);
    int nWin = FMAIN + eExt;
    if (t < nWin) {
        int p = B0 + t;
        int s = clampi(src[p], 0, N - 1);
        int d = clampi(sDst[t], 0, N - 1);
        long long erow = VIA_EID ? (long long)clampi(eid[p], 0, E - 1) : (long long)p;
        float xs[16], xd[16], ev[16];
        loadRow<TX>(X + (long long)s * 16, xs);
        loadRow<TX>(X + (long long)d * 16, xd);
        load16b(Ein + erow * 16, ev);
        float eo[16];
        edge_core(xs, xd, ev, sW, sB, sLg, sLb, eo, &sMS4[t * 5]);
        if (t < FMAIN) store16b(Eout + erow * 16, eo);
    }
    __syncthreads();
    // ---- node phase ----
    for (int d = dNodeLo + t; d < dhiN; d += NTHR) {
        float xv[16];
        loadRow<TX>(X + (long long)d * 16, xv);
        float num[16], den[16];
#pragma unroll
        for (int j = 0; j < 16; j++) { num[j] = 0.f; den[j] = 0.f; }
        int p0 = ofs[d], p1 = ofs[d + 1];
        for (int p = p0; p < p1; p++) {
            int q = clampi(p - B0, 0, FWIN - 1);
            const uint4* qq = &sMS4[q * 5];
            uint4 q0 = qq[0], q1 = qq[1], q2 = qq[2], q3 = qq[3];
            unsigned w[16] = {q0.x,q0.y,q0.z,q0.w, q1.x,q1.y,q1.z,q1.w,
                              q2.x,q2.y,q2.z,q2.w, q3.x,q3.y,q3.z,q3.w};
#pragma unroll
            for (int i = 0; i < 8; i++) {
                num[2*i]   += bfbits2f(w[i] & 0xFFFFu);
                num[2*i+1] += bfbits2f(w[i] >> 16);
                den[2*i]   += bfbits2f(w[8+i] & 0xFFFFu);
                den[2*i+1] += bfbits2f(w[8+i] >> 16);
            }
        }
        float tt[16]; float mu = 0.f;
#pragma unroll
        for (int j = 0; j < 16; j++) {
            float a = sB[16 + j] + num[j] / (den[j] + 1e-5f);
#pragma unroll
            for (int k = 0; k < 16; k++) a += xv[k] * sW[768 + k * 16 + j];
            tt[j] = a; mu += a;
        }
        mu *= (1.f / 16.f);
        float var = 0.f;
#pragma unroll
        for (int j = 0; j < 16; j++) { float dd2 = tt[j] - mu; var += dd2 * dd2; }
        var *= (1.f / 16.f);
        float r = rsqrtf(var + 1e-5f);
        float ov[16];
#pragma unroll
        for (int j = 0; j < 16; j++)
            ov[j] = xv[j] + siluf_((tt[j] - mu) * r * sLg[16 + j] + sLb[16 + j]);
        storeRow<TX>(Xn + (long long)d * 16, ov);
    }
}

// ---------- pooling: one block per graph (batch sorted, no atomics) ----------
__global__ void __launch_bounds__(256) k_pool2(
    const float* __restrict__ h, const int* __restrict__ batch, float* __restrict__ pooled)
{
    int g = blockIdx.x;
    int lo = 0, hi = N_ATM;
    while (lo < hi) { int m = (lo + hi) >> 1; if (batch[m] < g) lo = m + 1; else hi = m; }
    int s0 = lo;
    lo = 0; hi = N_ATM;
    while (lo < hi) { int m = (lo + hi) >> 1; if (batch[m] < g + 1) lo = m + 1; else hi = m; }
    int s1 = lo;
    float acc[16];
#pragma unroll
    for (int j = 0; j < 16; j++) acc[j] = 0.f;
    for (int i = s0 + threadIdx.x; i < s1; i += 256) {
        float v[16];
        load16f(h + (long long)i * 16, v);
#pragma unroll
        for (int j = 0; j < 16; j++) acc[j] += v[j];
    }
#pragma unroll
    for (int j = 0; j < 16; j++)
        for (int o = 32; o > 0; o >>= 1) acc[j] += __shfl_down(acc[j], o, 64);
    __shared__ float red[4][16];
    int wv = threadIdx.x >> 6, ln = threadIdx.x & 63;
    if (ln == 0)
#pragma unroll
        for (int j = 0; j < 16; j++) red[wv][j] = acc[j];
    __syncthreads();
    if (threadIdx.x < 16)
        pooled[g * 16 + threadIdx.x] = red[0][threadIdx.x] + red[1][threadIdx.x]
                                     + red[2][threadIdx.x] + red[3][threadIdx.x];
}

// ---------- head ----------
__global__ void __launch_bounds__(256) k_head(
    const float* __restrict__ pooled, const void* __restrict__ fp,
    const void* l1W, const void* l1b, const void* l2W, const void* l2b,
    const int* __restrict__ flags, void* __restrict__ out)
{
    __shared__ float sW[18 * 16], sb[16], s2W[16];
    int t = threadIdx.x, isbf = flags[0];
    for (int i = t; i < 288; i += 256) sW[i] = loadF(l1W, i, isbf);
    if (t < 16) { sb[t] = loadF(l1b, t, isbf); s2W[t] = loadF(l2W, t, isbf); }
    __syncthreads();
    int g = t;
    if (g >= N_GRAPHS) return;
    float in[18];
#pragma unroll
    for (int j = 0; j < 16; j++) in[j] = pooled[g * 16 + j];
    in[16] = loadF(fp, 2 * g, isbf);
    in[17] = loadF(fp, 2 * g + 1, isbf);
    float acc = loadF(l2b, 0, isbf);
#pragma unroll
    for (int j = 0; j < 16; j++) {
        float h = sb[j];
#pragma unroll
        for (int k = 0; k < 18; k++) h += in[k] * sW[k * 16 + j];
        h = (h > 0.f) ? h : 0.01f * h;
        acc += h * s2W[j];
    }
    if (isbf) ((bf16*)out)[g] = __float2bfloat16(acc);
    else      ((float*)out)[g] = acc;
}

extern "C" void kernel_launch(void* const* d_in, const int* in_sizes, int n_in,
                              void* d_out, int out_size, void* d_ws, size_t ws_size,
                              hipStream_t stream) {
    const int*  x_atm = (const int*)d_in[0];
    const void* x_bnd = d_in[1];
    const void* x_ang = d_in[2];
    const void* mask  = d_in[3];
    const int*  eiG   = (const int*)d_in[4];
    const int*  eiA   = (const int*)d_in[5];
    const int*  batch = (const int*)d_in[6];
    const void* fp    = d_in[7];
    const void* eW1 = d_in[8],  *eb1 = d_in[9],  *eW2 = d_in[10], *eb2 = d_in[11];
    const void* elg = d_in[12], *elb = d_in[13];
    const void* convW = d_in[14], *convB = d_in[15], *convLN = d_in[16];
    const void* l1W = d_in[17], *l1b = d_in[18], *l2W = d_in[19], *l2b = d_in[20];

    const int NB_L = N_ANG / FMAIN;   // 8192 blocks, line conv
    const int NB_A = N_BND / FMAIN;   // 4096 blocks, atom conv

    // Workspace layout — total 239,770,112 B (< proven-safe 241.2 MB)
    char* p = (char*)d_ws;
    int*   flags  = (int*)p;   p += 256;
    float* cw     = (float*)p; p += 7680 * 4;
    float* cb     = (float*)p; p += 192 * 4;
    float* cln    = (float*)p; p += 384 * 4;
    float* pooled = (float*)p; p += 4096 * 4;
    int*   bsum   = (int*)p;   p += 4096 * 4;
    int*   ownerL = (int*)p;   p += 8448 * 4;   // NB_L+1 = 8193 used
    int*   firstL = (int*)p;   p += 8448 * 4;
    int*   ownerA = (int*)p;   p += 4352 * 4;   // NB_A+1 = 4097 used
    int*   firstA = (int*)p;   p += 4352 * 4;
    int*   ofsB   = (int*)p;   p += (size_t)(N_BND + 256) * 4;  // +sentinel
    int*   srcB   = (int*)p;   p += (size_t)N_ANG * 4;
    int*   ofsA   = (int*)p;   p += (size_t)(N_ATM + 256) * 4;  // +sentinel
    int*   srcG   = (int*)p;   p += (size_t)N_BND * 4;
    int*   eidG   = (int*)p;   p += (size_t)N_BND * 4;
    float* atmA   = (float*)p; p += (size_t)N_ATM * 64;
    float* atmB   = (float*)p; p += (size_t)N_ATM * 64;
    bf16*  bndA   = (bf16*)p;  p += (size_t)N_BND * 32;
    bf16*  bndB   = (bf16*)p;  p += (size_t)N_BND * 32;
    bf16*  angA   = (bf16*)p;  p += (size_t)N_ANG * 32;
    bf16*  angB   = (bf16*)p;
    // overlay: cursors + angle slot map live in bndB, which is first written in
    // round-1 line node phase (long after CSR build + encoders are done)
    int*   curB   = (int*)bndB;          // N_BND ints (counts, then scatter cursor)
    int*   curA   = curB + N_BND;        // N_ATM ints
    int*   posB   = curA + N_ATM;        // N_ANG ints (angle -> slot, encoder only)

    // dtype detection + conv params
    k_zero_int<<<1, 64, 0, stream>>>(flags, 64);
    k_detect<<<512, 256, 0, stream>>>(elg, (const unsigned*)mask, flags);
    k_cvt_any<<<30, 256, 0, stream>>>(convW, cw, 7680, flags);
    k_cvt_any<<<1, 256, 0, stream>>>(convB, cb, 192, flags);
    k_cvt_any<<<2, 256, 0, stream>>>(convLN, cln, 384, flags);

    // CSR: line graph (bonds <- angle edges)
    k_zero_int<<<N_BND / 256, 256, 0, stream>>>(curB, N_BND);
    k_count<<<N_ANG / 256, 256, 0, stream>>>(eiA + N_ANG, curB, N_ANG, N_BND);
    k_scan_local<<<N_BND / 256, 256, 0, stream>>>(curB, ofsB, bsum, N_BND);
    k_scan_bsum<<<1, 256, 0, stream>>>(bsum, N_BND / 256);
    k_scan_add2<<<N_BND / 256, 256, 0, stream>>>(ofsB, bsum, curB, N_BND, N_ANG);
    k_scatter_line2<<<N_ANG / 256, 256, 0, stream>>>(eiA, eiA + N_ANG, curB, srcB, posB,
                                                     N_ANG, N_BND);
    k_blkrange<<<(NB_L + 256) / 256, 256, 0, stream>>>(ofsB, N_BND, NB_L + 1, ownerL, firstL);

    // CSR: atom graph (atoms <- bond edges)
    k_zero_int<<<N_ATM / 256, 256, 0, stream>>>(curA, N_ATM);
    k_count<<<N_BND / 256, 256, 0, stream>>>(eiG + N_BND, curA, N_BND, N_ATM);
    k_scan_local<<<N_ATM / 256, 256, 0, stream>>>(curA, ofsA, bsum, N_ATM);
    k_scan_bsum<<<1, 256, 0, stream>>>(bsum, N_ATM / 256);
    k_scan_add2<<<N_ATM / 256, 256, 0, stream>>>(ofsA, bsum, curA, N_ATM, N_BND);
    k_scatter_atom2<<<N_BND / 256, 256, 0, stream>>>(eiG, eiG + N_BND, curA, srcG, eidG,
                                                     N_BND, N_ATM, N_ATM);
    k_blkrange<<<(NB_A + 256) / 256, 256, 0, stream>>>(ofsA, N_ATM, NB_A + 1, ownerA, firstA);

    // encoders (k_enc_ang consumes posB; bndB overlay dies here)
    k_enc_atm<<<N_ATM / 256, 256, 0, stream>>>(x_atm, eW1, eb1, eW2, eb2, elg, elb, flags, atmA);
    k_enc_bnd<<<N_BND / 256, 256, 0, stream>>>(x_bnd, eW1, eb1, eW2, eb2, elg, elb, flags, bndA);
    k_enc_ang<<<N_ANG / 256, 256, 0, stream>>>(x_ang, mask, eW1, eb1, eW2, eb2, elg, elb, flags,
                                               posB, angA);

    // processor: per round, bonds go A->B (line) then B->A (atom): valid bonds
    // are always in bndA at round start. Angles and atoms ping-pong per round.
    float* atmCur = atmA; float* atmOth = atmB;
    bf16*  angCur = angA; bf16*  angOth = angB;
    for (int c = 0; c < 3; c++) {
        const float* Wl = cw + (size_t)(c * 2 + 0) * 1280;
        const float* Bl = cb + (size_t)(c * 2 + 0) * 32;
        const float* Ll = cln + (size_t)(c * 2 + 0) * 64;
        k_fused<bf16, false><<<NB_L, NTHR, 0, stream>>>(
            bndA, bndB, angCur, angOth, srcB, (const int*)nullptr,
            ofsB, ownerL, firstL, Wl, Bl, Ll, N_ANG, N_BND, NB_L);
        const float* Wa = cw + (size_t)(c * 2 + 1) * 1280;
        const float* Ba = cb + (size_t)(c * 2 + 1) * 32;
        const float* La = cln + (size_t)(c * 2 + 1) * 64;
        k_fused<float, true><<<NB_A, NTHR, 0, stream>>>(
            atmCur, atmOth, bndB, bndA, srcG, eidG,
            ofsA, ownerA, firstA, Wa, Ba, La, N_BND, N_ATM, NB_A);
        float* ft = atmCur; atmCur = atmOth; atmOth = ft;
        bf16*  bt = angCur; angCur = angOth; angOth = bt;
    }

    k_pool2<<<N_GRAPHS, 256, 0, stream>>>(atmCur, batch, pooled);
    k_head<<<1, 256, 0, stream>>>(pooled, fp, l1W, l1b, l2W, l2b, flags, d_out);
}

// Round 6
// 4241.525 us; speedup vs baseline: 1.6212x; 1.6212x over previous
//
#include <hip/hip_runtime.h>
#include <hip/hip_bf16.h>

#define N_ATM 131072
#define N_BND 1048576
#define N_ANG 2097152
#define N_GRAPHS 256
#define PI_F 3.14159265358979323846f

#define FMAIN 256
#define FEXT 64
#define FWIN (FMAIN + FEXT)   // 320 slots per block window
#define NTHR 320              // fused kernel block size: one thread per window slot

typedef __hip_bfloat16 bf16;

__device__ __forceinline__ int clampi(int v, int lo, int hi) {
    return v < lo ? lo : (v > hi ? hi : v);
}
__device__ __forceinline__ float b2f(bf16 v) { return __bfloat162float(v); }
__device__ __forceinline__ float sigmoidf_(float x) { return 1.0f / (1.0f + __expf(-x)); }
__device__ __forceinline__ float siluf_(float x) { return x / (1.0f + __expf(-x)); }

__device__ __forceinline__ float loadF(const void* p, long long i, int isbf) {
    return isbf ? b2f(((const bf16*)p)[i]) : ((const float*)p)[i];
}
__device__ __forceinline__ float bfbits2f(unsigned lo16) {
    union { unsigned u; float f; } c; c.u = lo16 << 16; return c.f;
}
__device__ __forceinline__ unsigned f2bfbits(float f) {
    union { float f; unsigned u; } c; c.f = f;
    unsigned u = c.u + 0x7FFFu + ((c.u >> 16) & 1u);  // RNE
    return u >> 16;
}

// ---- 16-wide row IO ----
__device__ __forceinline__ void load16f(const float* p, float* r) {
    const float4* q = (const float4*)p;
#pragma unroll
    for (int i = 0; i < 4; i++) { float4 v = q[i]; r[4*i]=v.x; r[4*i+1]=v.y; r[4*i+2]=v.z; r[4*i+3]=v.w; }
}
__device__ __forceinline__ void store16f(float* p, const float* r) {
    float4* q = (float4*)p;
#pragma unroll
    for (int i = 0; i < 4; i++) q[i] = make_float4(r[4*i], r[4*i+1], r[4*i+2], r[4*i+3]);
}
__device__ __forceinline__ void load16b(const bf16* p, float* r) {
    uint4 a = ((const uint4*)p)[0];
    uint4 b = ((const uint4*)p)[1];
    unsigned w[8] = {a.x, a.y, a.z, a.w, b.x, b.y, b.z, b.w};
#pragma unroll
    for (int i = 0; i < 8; i++) {
        r[2*i] = bfbits2f(w[i] & 0xFFFFu);
        union { unsigned u; float f; } c; c.u = w[i] & 0xFFFF0000u;
        r[2*i+1] = c.f;
    }
}
__device__ __forceinline__ void store16b(bf16* p, const float* r) {
    unsigned w[8];
#pragma unroll
    for (int i = 0; i < 8; i++)
        w[i] = f2bfbits(r[2*i]) | (f2bfbits(r[2*i+1]) << 16);
    ((uint4*)p)[0] = make_uint4(w[0], w[1], w[2], w[3]);
    ((uint4*)p)[1] = make_uint4(w[4], w[5], w[6], w[7]);
}

template <typename TX>
__device__ __forceinline__ void loadRow(const TX* p, float* r);
template <> __device__ __forceinline__ void loadRow<float>(const float* p, float* r) { load16f(p, r); }
template <> __device__ __forceinline__ void loadRow<bf16>(const bf16* p, float* r) { load16b(p, r); }
template <typename TX>
__device__ __forceinline__ void storeRow(TX* p, const float* r);
template <> __device__ __forceinline__ void storeRow<float>(float* p, const float* r) { store16f(p, r); }
template <> __device__ __forceinline__ void storeRow<bf16>(bf16* p, const float* r) { store16b(p, r); }

// ---------- utility ----------
__global__ void __launch_bounds__(256) k_zero_int(int* __restrict__ p, int n) {
    int i = blockIdx.x * 256 + threadIdx.x;
    if (i < n) p[i] = 0;
}

// flags[0]=1 if float tensors are bf16; flags[1]=1 if mask is byte-bools
__global__ void __launch_bounds__(256) k_detect(const void* lng, const unsigned* __restrict__ mask,
                                                int* flags) {
    int i = blockIdx.x * 256 + threadIdx.x;
    if (i == 0) flags[0] = (*(const unsigned*)lng == 0x3F803F80u) ? 1 : 0;
    int bad = 0;
    for (int j = i; j < 512 * 1024; j += 512 * 256)
        if (mask[j] > 1u) bad = 1;
    if (bad) atomicOr(&flags[1], 1);
}

__global__ void k_cvt_any(const void* __restrict__ src, float* __restrict__ dst, int n,
                          const int* __restrict__ flags) {
    int i = blockIdx.x * blockDim.x + threadIdx.x;
    if (i < n) dst[i] = loadF(src, i, flags[0]);
}

// ---------- CSR build ----------
__global__ void __launch_bounds__(256) k_count(const int* __restrict__ dst, int* __restrict__ cnt,
                                               int E, int n) {
    int i = blockIdx.x * 256 + threadIdx.x;
    if (i >= E) return;
    atomicAdd(&cnt[clampi(dst[i], 0, n - 1)], 1);
}
__global__ void __launch_bounds__(256) k_scan_local(const int* __restrict__ cnt, int* __restrict__ ofs,
                                                    int* __restrict__ bsum, int n) {
    __shared__ int s[256];
    int t = threadIdx.x, i = blockIdx.x * 256 + t;
    int v = (i < n) ? cnt[i] : 0;
    s[t] = v; __syncthreads();
    for (int o = 1; o < 256; o <<= 1) {
        int add = (t >= o) ? s[t - o] : 0;
        __syncthreads();
        s[t] += add;
        __syncthreads();
    }
    if (i < n) ofs[i] = s[t] - v;
    if (t == 255) bsum[blockIdx.x] = s[255];
}
__global__ void __launch_bounds__(256) k_scan_bsum(int* __restrict__ bsum, int nb) {
    __shared__ int s[256];
    __shared__ int run;
    int t = threadIdx.x;
    if (t == 0) run = 0;
    __syncthreads();
    for (int base = 0; base < nb; base += 256) {
        int i = base + t;
        int v = (i < nb) ? bsum[i] : 0;
        s[t] = v; __syncthreads();
        for (int o = 1; o < 256; o <<= 1) {
            int add = (t >= o) ? s[t - o] : 0;
            __syncthreads();
            s[t] += add;
            __syncthreads();
        }
        if (i < nb) bsum[i] = run + s[t] - v;
        __syncthreads();
        if (t == 0) run += s[255];
        __syncthreads();
    }
}
// finalizes ofs (adds block sums), copies cursor, writes sentinel ofs[n]=total
__global__ void __launch_bounds__(256) k_scan_add2(int* __restrict__ ofs, const int* __restrict__ bsum,
                                                   int* __restrict__ cursor, int n, int total) {
    int i = blockIdx.x * 256 + threadIdx.x;
    if (i < n) { int v = ofs[i] + bsum[blockIdx.x]; ofs[i] = v; cursor[i] = v; }
    if (i == 0) ofs[n] = total;
}
// line graph: permuted src + original->slot map (for angle encoder)
__global__ void __launch_bounds__(256) k_scatter_line2(
    const int* __restrict__ src, const int* __restrict__ dst, int* __restrict__ cur,
    int* __restrict__ srcP, int* __restrict__ pos, int E, int n)
{
    int i = blockIdx.x * 256 + threadIdx.x;
    if (i >= E) return;
    int d = clampi(dst[i], 0, n - 1);
    int s = clampi(src[i], 0, n - 1);
    int p = clampi(atomicAdd(&cur[d], 1), 0, E - 1);
    srcP[p] = s; pos[i] = p;
}
// atom graph: permuted src + original bond id per slot
__global__ void __launch_bounds__(256) k_scatter_atom2(
    const int* __restrict__ src, const int* __restrict__ dst, int* __restrict__ cur,
    int* __restrict__ srcP, int* __restrict__ eidP, int E, int n, int ns)
{
    int i = blockIdx.x * 256 + threadIdx.x;
    if (i >= E) return;
    int d = clampi(dst[i], 0, n - 1);
    int s = clampi(src[i], 0, ns - 1);
    int p = clampi(atomicAdd(&cur[d], 1), 0, E - 1);
    srcP[p] = s; eidP[p] = i;
}
// per-block-boundary node ranges (CSR static across rounds -> compute once)
// owner[b] = last d with ofs[d] <= b*FMAIN ; first[b] = first d with ofs[d] >= b*FMAIN
__global__ void __launch_bounds__(256) k_blkrange(const int* __restrict__ ofs, int N, int nbp1,
                                                  int* __restrict__ owner, int* __restrict__ first) {
    int b = blockIdx.x * 256 + threadIdx.x;
    if (b >= nbp1) return;
    int B0 = b * FMAIN;
    int lo = 0, hi = N;
    while (lo < hi) { int m = (lo + hi) >> 1; if (ofs[m] < B0) lo = m + 1; else hi = m; }
    first[b] = lo;
    lo = 0; hi = N + 1;
    while (lo < hi) { int m = (lo + hi) >> 1; if (ofs[m] <= B0) lo = m + 1; else hi = m; }
    owner[b] = (lo - 1) < 0 ? 0 : (lo - 1);
}

// ---------- encoders ----------
__global__ void __launch_bounds__(256) k_enc_atm(
    const int* __restrict__ sp_in,
    const void* W1, const void* b1, const void* W2, const void* b2,
    const void* g, const void* be, const int* __restrict__ flags,
    float* __restrict__ out)
{
    __shared__ float sW1[256], sW2[256], sb1[16], sb2[16], sg[16], sbe[16];
    int t = threadIdx.x, isbf = flags[0];
    sW1[t] = loadF(W1, t, isbf); sW2[t] = loadF(W2, t, isbf);
    if (t < 16) { sb1[t]=loadF(b1,t,isbf); sb2[t]=loadF(b2,t,isbf); sg[t]=loadF(g,t,isbf); sbe[t]=loadF(be,t,isbf); }
    __syncthreads();
    int i = blockIdx.x * 256 + t;
    if (i >= N_ATM) return;
    int sp = clampi(sp_in[i], 0, 15);
    float h[16];
#pragma unroll
    for (int j = 0; j < 16; j++) h[j] = siluf_(sW1[sp * 16 + j] + sb1[j]);
    float o[16]; float mu = 0.f;
#pragma unroll
    for (int j = 0; j < 16; j++) {
        float a = sb2[j];
#pragma unroll
        for (int k = 0; k < 16; k++) a += h[k] * sW2[k * 16 + j];
        o[j] = a; mu += a;
    }
    mu *= (1.f / 16.f);
    float var = 0.f;
#pragma unroll
    for (int j = 0; j < 16; j++) { float d = o[j] - mu; var += d * d; }
    var *= (1.f / 16.f);
    float r = rsqrtf(var + 1e-5f);
    float ov[16];
#pragma unroll
    for (int j = 0; j < 16; j++) ov[j] = (o[j] - mu) * r * sg[j] + sbe[j];
    store16f(out + (long long)i * 16, ov);
}

__global__ void __launch_bounds__(256) k_enc_bnd(
    const void* __restrict__ xb,
    const void* W1, const void* b1, const void* W2, const void* b2,
    const void* g, const void* be, const int* __restrict__ flags,
    bf16* __restrict__ out)
{
    __shared__ float sW1[256], sW2[256], sb1[16], sb2[16], sg[16], sbe[16];
    int t = threadIdx.x, isbf = flags[0];
    sW1[t] = loadF(W1, 256 + t, isbf); sW2[t] = loadF(W2, 256 + t, isbf);
    if (t < 16) { sb1[t]=loadF(b1,16+t,isbf); sb2[t]=loadF(b2,16+t,isbf); sg[t]=loadF(g,16+t,isbf); sbe[t]=loadF(be,16+t,isbf); }
    __syncthreads();
    int i = blockIdx.x * 256 + t;
    if (i >= N_BND) return;
    float x = loadF(xb, i, isbf) + 1e-5f;
    const float c = 0.6324555320336759f; // sqrt(2/5)
    float inv = c / x;
    float feat[16];
#pragma unroll
    for (int k = 0; k < 16; k++) feat[k] = __sinf((float)(k + 1) * PI_F * x * 0.2f) * inv;
    float h[16];
#pragma unroll
    for (int j = 0; j < 16; j++) {
        float a = sb1[j];
#pragma unroll
        for (int k = 0; k < 16; k++) a += feat[k] * sW1[k * 16 + j];
        h[j] = siluf_(a);
    }
    float o[16]; float mu = 0.f;
#pragma unroll
    for (int j = 0; j < 16; j++) {
        float a = sb2[j];
#pragma unroll
        for (int k = 0; k < 16; k++) a += h[k] * sW2[k * 16 + j];
        o[j] = a; mu += a;
    }
    mu *= (1.f / 16.f);
    float var = 0.f;
#pragma unroll
    for (int j = 0; j < 16; j++) { float d = o[j] - mu; var += d * d; }
    var *= (1.f / 16.f);
    float r = rsqrtf(var + 1e-5f);
    float ov[16];
#pragma unroll
    for (int j = 0; j < 16; j++) ov[j] = (o[j] - mu) * r * sg[j] + sbe[j];
    store16b(out + (long long)i * 16, ov);
}

// angle encoder: writes row to CSR slot pos[i]
__global__ void __launch_bounds__(256) k_enc_ang(
    const void* __restrict__ xa, const void* __restrict__ mask,
    const void* W1, const void* b1, const void* W2, const void* b2,
    const void* g, const void* be, const int* __restrict__ flags,
    const int* __restrict__ pos, bf16* __restrict__ out)
{
    __shared__ float sW1[512], sW2[512], sb1[32], sb2[32], sg[32], sbe[32];
    int t = threadIdx.x, isbf = flags[0], mbyte = flags[1];
    for (int i = t; i < 512; i += 256) { sW1[i] = loadF(W1, 512 + i, isbf); sW2[i] = loadF(W2, 512 + i, isbf); }
    if (t < 32) { sb1[t]=loadF(b1,32+t,isbf); sb2[t]=loadF(b2,32+t,isbf); sg[t]=loadF(g,32+t,isbf); sbe[t]=loadF(be,32+t,isbf); }
    __syncthreads();
    int i = blockIdx.x * 256 + t;
    if (i >= N_ANG) return;
    int m = mbyte ? (((const unsigned char*)mask)[i] != 0) : (((const int*)mask)[i] != 0);
    float x = loadF(xa, i, isbf);
    float gam = m ? 2.3873241463784303f : 4.7746482927568605f;   // 15/(2pi) : 15/pi
    float c0  = m ? -PI_F : 0.0f;
    float dc  = m ? 0.41887902047863906f : 0.20943951023931953f; // 2pi/15 : pi/15
    int wo = m * 256, vo = m * 16;
    float feat[16];
#pragma unroll
    for (int k = 0; k < 16; k++) {
        float d = gam * (x - (c0 + (float)k * dc));
        feat[k] = __expf(-d * d);
    }
    float h[16];
#pragma unroll
    for (int j = 0; j < 16; j++) {
        float a = sb1[vo + j];
#pragma unroll
        for (int k = 0; k < 16; k++) a += feat[k] * sW1[wo + k * 16 + j];
        h[j] = siluf_(a);
    }
    float o[16]; float mu = 0.f;
#pragma unroll
    for (int j = 0; j < 16; j++) {
        float a = sb2[vo + j];
#pragma unroll
        for (int k = 0; k < 16; k++) a += h[k] * sW2[wo + k * 16 + j];
        o[j] = a; mu += a;
    }
    mu *= (1.f / 16.f);
    float var = 0.f;
#pragma unroll
    for (int j = 0; j < 16; j++) { float d = o[j] - mu; var += d * d; }
    var *= (1.f / 16.f);
    float r = rsqrtf(var + 1e-5f);
    float ov[16];
#pragma unroll
    for (int j = 0; j < 16; j++) ov[j] = (o[j] - mu) * r * sg[vo + j] + sbe[vo + j];
    store16b(out + (long long)clampi(pos[i], 0, N_ANG - 1) * 16, ov);
}

// ---------- fused edge+node conv ----------
// Block b owns CSR slots [b*256, b*256+256); 320 threads cover main + <=64 extension
// slots (the straddler node's tail; no Eout write there - the owning block writes those
// rows). (msg,sigma) staged in LDS as 4x uint4 per slot, slot stride 5 uint4s (pad ->
// banks spread). Slot layout: [0..1]=msg (16 bf16), [2..3]=sigma (16 bf16).
// e fully ping-ponged (Ein read-only) so extension reads never race e_new writes.
// VIA_EID: e rows accessed through eid[] (atom graph: bonds stored in natural order).
// Node phase: all d with ofs[d] in [B0, B0+256); last block absorbs trailing deg-0
// nodes (num=den=0 -> matches reference).
// REGISTER-DIET DESIGN (R5 post-mortem: ~2.8 GB scratch traffic matched node-phase
// accumulator demotion): every phase keeps peak live set <= ~64 floats. Edge phase is
// multi-pass (mm then z built term-family by term-family, inputs die as consumed);
// node phase accumulates straight from uint4 (no staging array) and loads xv AFTER
// the reduce loop. LDS accessed by direct array indexing (addrspace visible).
template <typename TX, bool VIA_EID>
__global__ void __launch_bounds__(NTHR) k_fused(
    const TX* __restrict__ X, TX* __restrict__ Xn,
    const bf16* __restrict__ Ein, bf16* __restrict__ Eout,
    const int* __restrict__ src, const int* __restrict__ eid,
    const int* __restrict__ ofs, const int* __restrict__ owner, const int* __restrict__ first,
    const float* __restrict__ W, const float* __restrict__ Bp, const float* __restrict__ L,
    int E, int N, int nb)
{
    __shared__ float sW[1280], sB[32], sLg[32], sLb[32];
    __shared__ uint4 sMS4[FWIN * 5];   // slot w -> sMS4[w*5 .. w*5+3], +1 pad
    __shared__ int sDst[FWIN];
    int t = threadIdx.x;
    int b = blockIdx.x;
    int B0 = b * FMAIN;
    for (int i = t; i < 1280; i += NTHR) sW[i] = W[i];
    if (t < 16) {
        sB[t] = Bp[t];        sB[16 + t] = Bp[16 + t];
        sLg[t] = L[32 + t];   sLb[t] = L[48 + t];       // edge LN
        sLg[16 + t] = L[t];   sLb[16 + t] = L[16 + t];  // node LN
    }
    int d0      = owner[b];
    int dNodeLo = first[b];
    int dhi     = first[b + 1];
    int dhiN    = (b == nb - 1) ? N : dhi;
    // fill slot -> dst map for the window
    for (int dd = d0 + t; dd < dhi; dd += NTHR) {
        int a = ofs[dd], e2 = ofs[dd + 1];
        int lo2 = a < B0 ? B0 : a;
        int hi2 = e2 > B0 + FWIN ? B0 + FWIN : e2;
        for (int p = lo2; p < hi2; p++) sDst[p - B0] = dd;
    }
    __syncthreads();
    // ---- edge phase: one slot per thread, multi-pass (minimal liveness) ----
    int eExt = ofs[clampi(dhi, 0, N)] - (B0 + FMAIN);
    eExt = eExt < 0 ? 0 : (eExt > FEXT ? FEXT : eExt);
    int nWin = FMAIN + eExt;
    if (t < nWin) {
        int p = B0 + t;
        long long erow = VIA_EID ? (long long)clampi(eid[p], 0, E - 1) : (long long)p;
        float z[16], mm[16];
        // pass 1: xs -> mm and z  (xs dies after)
        {
            float xs[16];
            {
                int s = clampi(src[p], 0, N - 1);
                loadRow<TX>(X + (long long)s * 16, xs);
            }
#pragma unroll
            for (int j = 0; j < 16; j++) { mm[j] = 0.f; z[j] = sB[j]; }
#pragma unroll
            for (int k = 0; k < 16; k++) {
                float a = xs[k];
#pragma unroll
                for (int j = 0; j < 16; j++) {
                    mm[j] += a * sW[1024 + k * 16 + j];
                    z[j]  += a * sW[k * 16 + j];
                }
            }
        }
        // pass 2: xd -> z  (xd dies after)
        {
            float xd[16];
            {
                int d = clampi(sDst[t], 0, N - 1);
                loadRow<TX>(X + (long long)d * 16, xd);
            }
#pragma unroll
            for (int k = 0; k < 16; k++) {
                float a = xd[k];
#pragma unroll
                for (int j = 0; j < 16; j++) z[j] += a * sW[256 + k * 16 + j];
            }
        }
        // pass 3: ev -> z  (ev stays live for the residual)
        float ev[16];
        load16b(Ein + erow * 16, ev);
#pragma unroll
        for (int k = 0; k < 16; k++) {
            float a = ev[k];
#pragma unroll
            for (int j = 0; j < 16; j++) z[j] += a * sW[512 + k * 16 + j];
        }
        // pack (sigma*mm, sigma) -> LDS directly  (mm dies)
        {
            unsigned pm[8], ps[8];
#pragma unroll
            for (int i = 0; i < 8; i++) {
                float a0 = sigmoidf_(z[2*i]);
                float a1 = sigmoidf_(z[2*i+1]);
                pm[i] = f2bfbits(a0 * mm[2*i]) | (f2bfbits(a1 * mm[2*i+1]) << 16);
                ps[i] = f2bfbits(a0)           | (f2bfbits(a1) << 16);
            }
            sMS4[t * 5 + 0] = make_uint4(pm[0], pm[1], pm[2], pm[3]);
            sMS4[t * 5 + 1] = make_uint4(pm[4], pm[5], pm[6], pm[7]);
            sMS4[t * 5 + 2] = make_uint4(ps[0], ps[1], ps[2], ps[3]);
            sMS4[t * 5 + 3] = make_uint4(ps[4], ps[5], ps[6], ps[7]);
        }
        // LN + residual -> Eout (only main slots write)
        if (t < FMAIN) {
            float mu = 0.f;
#pragma unroll
            for (int j = 0; j < 16; j++) mu += z[j];
            mu *= (1.f / 16.f);
            float var = 0.f;
#pragma unroll
            for (int j = 0; j < 16; j++) { float dd = z[j] - mu; var += dd * dd; }
            var *= (1.f / 16.f);
            float r = rsqrtf(var + 1e-5f);
            float eo[16];
#pragma unroll
            for (int j = 0; j < 16; j++)
                eo[j] = ev[j] + siluf_((z[j] - mu) * r * sLg[j] + sLb[j]);
            store16b(Eout + erow * 16, eo);
        }
    }
    __syncthreads();
    // ---- node phase (lean loop: only num/den live across the backedge) ----
    for (int d = dNodeLo + t; d < dhiN; d += NTHR) {
        float num[16], den[16];
#pragma unroll
        for (int j = 0; j < 16; j++) { num[j] = 0.f; den[j] = 0.f; }
        int p0 = ofs[d], p1 = ofs[d + 1];
        for (int p = p0; p < p1; p++) {
            int q5 = clampi(p - B0, 0, FWIN - 1) * 5;
            {
                uint4 q0 = sMS4[q5 + 0];
                num[0] += bfbits2f(q0.x & 0xFFFFu); num[1] += bfbits2f(q0.x >> 16);
                num[2] += bfbits2f(q0.y & 0xFFFFu); num[3] += bfbits2f(q0.y >> 16);
                num[4] += bfbits2f(q0.z & 0xFFFFu); num[5] += bfbits2f(q0.z >> 16);
                num[6] += bfbits2f(q0.w & 0xFFFFu); num[7] += bfbits2f(q0.w >> 16);
            }
            {
                uint4 q1 = sMS4[q5 + 1];
                num[8]  += bfbits2f(q1.x & 0xFFFFu); num[9]  += bfbits2f(q1.x >> 16);
                num[10] += bfbits2f(q1.y & 0xFFFFu); num[11] += bfbits2f(q1.y >> 16);
                num[12] += bfbits2f(q1.z & 0xFFFFu); num[13] += bfbits2f(q1.z >> 16);
                num[14] += bfbits2f(q1.w & 0xFFFFu); num[15] += bfbits2f(q1.w >> 16);
            }
            {
                uint4 q2 = sMS4[q5 + 2];
                den[0] += bfbits2f(q2.x & 0xFFFFu); den[1] += bfbits2f(q2.x >> 16);
                den[2] += bfbits2f(q2.y & 0xFFFFu); den[3] += bfbits2f(q2.y >> 16);
                den[4] += bfbits2f(q2.z & 0xFFFFu); den[5] += bfbits2f(q2.z >> 16);
                den[6] += bfbits2f(q2.w & 0xFFFFu); den[7] += bfbits2f(q2.w >> 16);
            }
            {
                uint4 q3 = sMS4[q5 + 3];
                den[8]  += bfbits2f(q3.x & 0xFFFFu); den[9]  += bfbits2f(q3.x >> 16);
                den[10] += bfbits2f(q3.y & 0xFFFFu); den[11] += bfbits2f(q3.y >> 16);
                den[12] += bfbits2f(q3.z & 0xFFFFu); den[13] += bfbits2f(q3.z >> 16);
                den[14] += bfbits2f(q3.w & 0xFFFFu); den[15] += bfbits2f(q3.w >> 16);
            }
        }
        // fold num/den, then bring in xv (NOT live during the loop above)
        float xv[16];
        loadRow<TX>(X + (long long)d * 16, xv);
        float tt[16]; float mu = 0.f;
#pragma unroll
        for (int j = 0; j < 16; j++) {
            float a = sB[16 + j] + num[j] / (den[j] + 1e-5f);
#pragma unroll
            for (int k = 0; k < 16; k++) a += xv[k] * sW[768 + k * 16 + j];
            tt[j] = a; mu += a;
        }
        mu *= (1.f / 16.f);
        float var = 0.f;
#pragma unroll
        for (int j = 0; j < 16; j++) { float dd2 = tt[j] - mu; var += dd2 * dd2; }
        var *= (1.f / 16.f);
        float r = rsqrtf(var + 1e-5f);
        float ov[16];
#pragma unroll
        for (int j = 0; j < 16; j++)
            ov[j] = xv[j] + siluf_((tt[j] - mu) * r * sLg[16 + j] + sLb[16 + j]);
        storeRow<TX>(Xn + (long long)d * 16, ov);
    }
}

// ---------- pooling: one block per graph (batch sorted, no atomics) ----------
__global__ void __launch_bounds__(256) k_pool2(
    const float* __restrict__ h, const int* __restrict__ batch, float* __restrict__ pooled)
{
    int g = blockIdx.x;
    int lo = 0, hi = N_ATM;
    while (lo < hi) { int m = (lo + hi) >> 1; if (batch[m] < g) lo = m + 1; else hi = m; }
    int s0 = lo;
    lo = 0; hi = N_ATM;
    while (lo < hi) { int m = (lo + hi) >> 1; if (batch[m] < g + 1) lo = m + 1; else hi = m; }
    int s1 = lo;
    float acc[16];
#pragma unroll
    for (int j = 0; j < 16; j++) acc[j] = 0.f;
    for (int i = s0 + threadIdx.x; i < s1; i += 256) {
        float v[16];
        load16f(h + (long long)i * 16, v);
#pragma unroll
        for (int j = 0; j < 16; j++) acc[j] += v[j];
    }
#pragma unroll
    for (int j = 0; j < 16; j++)
        for (int o = 32; o > 0; o >>= 1) acc[j] += __shfl_down(acc[j], o, 64);
    __shared__ float red[4][16];
    int wv = threadIdx.x >> 6, ln = threadIdx.x & 63;
    if (ln == 0)
#pragma unroll
        for (int j = 0; j < 16; j++) red[wv][j] = acc[j];
    __syncthreads();
    if (threadIdx.x < 16)
        pooled[g * 16 + threadIdx.x] = red[0][threadIdx.x] + red[1][threadIdx.x]
                                     + red[2][threadIdx.x] + red[3][threadIdx.x];
}

// ---------- head ----------
__global__ void __launch_bounds__(256) k_head(
    const float* __restrict__ pooled, const void* __restrict__ fp,
    const void* l1W, const void* l1b, const void* l2W, const void* l2b,
    const int* __restrict__ flags, void* __restrict__ out)
{
    __shared__ float sW[18 * 16], sb[16], s2W[16];
    int t = threadIdx.x, isbf = flags[0];
    for (int i = t; i < 288; i += 256) sW[i] = loadF(l1W, i, isbf);
    if (t < 16) { sb[t] = loadF(l1b, t, isbf); s2W[t] = loadF(l2W, t, isbf); }
    __syncthreads();
    int g = t;
    if (g >= N_GRAPHS) return;
    float in[18];
#pragma unroll
    for (int j = 0; j < 16; j++) in[j] = pooled[g * 16 + j];
    in[16] = loadF(fp, 2 * g, isbf);
    in[17] = loadF(fp, 2 * g + 1, isbf);
    float acc = loadF(l2b, 0, isbf);
#pragma unroll
    for (int j = 0; j < 16; j++) {
        float h = sb[j];
#pragma unroll
        for (int k = 0; k < 18; k++) h += in[k] * sW[k * 16 + j];
        h = (h > 0.f) ? h : 0.01f * h;
        acc += h * s2W[j];
    }
    if (isbf) ((bf16*)out)[g] = __float2bfloat16(acc);
    else      ((float*)out)[g] = acc;
}

extern "C" void kernel_launch(void* const* d_in, const int* in_sizes, int n_in,
                              void* d_out, int out_size, void* d_ws, size_t ws_size,
                              hipStream_t stream) {
    const int*  x_atm = (const int*)d_in[0];
    const void* x_bnd = d_in[1];
    const void* x_ang = d_in[2];
    const void* mask  = d_in[3];
    const int*  eiG   = (const int*)d_in[4];
    const int*  eiA   = (const int*)d_in[5];
    const int*  batch = (const int*)d_in[6];
    const void* fp    = d_in[7];
    const void* eW1 = d_in[8],  *eb1 = d_in[9],  *eW2 = d_in[10], *eb2 = d_in[11];
    const void* elg = d_in[12], *elb = d_in[13];
    const void* convW = d_in[14], *convB = d_in[15], *convLN = d_in[16];
    const void* l1W = d_in[17], *l1b = d_in[18], *l2W = d_in[19], *l2b = d_in[20];

    const int NB_L = N_ANG / FMAIN;   // 8192 blocks, line conv
    const int NB_A = N_BND / FMAIN;   // 4096 blocks, atom conv

    // Workspace layout — total 239,770,112 B (< proven-safe 241.2 MB)
    char* p = (char*)d_ws;
    int*   flags  = (int*)p;   p += 256;
    float* cw     = (float*)p; p += 7680 * 4;
    float* cb     = (float*)p; p += 192 * 4;
    float* cln    = (float*)p; p += 384 * 4;
    float* pooled = (float*)p; p += 4096 * 4;
    int*   bsum   = (int*)p;   p += 4096 * 4;
    int*   ownerL = (int*)p;   p += 8448 * 4;   // NB_L+1 = 8193 used
    int*   firstL = (int*)p;   p += 8448 * 4;
    int*   ownerA = (int*)p;   p += 4352 * 4;   // NB_A+1 = 4097 used
    int*   firstA = (int*)p;   p += 4352 * 4;
    int*   ofsB   = (int*)p;   p += (size_t)(N_BND + 256) * 4;  // +sentinel
    int*   srcB   = (int*)p;   p += (size_t)N_ANG * 4;
    int*   ofsA   = (int*)p;   p += (size_t)(N_ATM + 256) * 4;  // +sentinel
    int*   srcG   = (int*)p;   p += (size_t)N_BND * 4;
    int*   eidG   = (int*)p;   p += (size_t)N_BND * 4;
    float* atmA   = (float*)p; p += (size_t)N_ATM * 64;
    float* atmB   = (float*)p; p += (size_t)N_ATM * 64;
    bf16*  bndA   = (bf16*)p;  p += (size_t)N_BND * 32;
    bf16*  bndB   = (bf16*)p;  p += (size_t)N_BND * 32;
    bf16*  angA   = (bf16*)p;  p += (size_t)N_ANG * 32;
    bf16*  angB   = (bf16*)p;
    // overlay: cursors + angle slot map live in bndB, which is first written in
    // round-1 line node phase (long after CSR build + encoders are done)
    int*   curB   = (int*)bndB;          // N_BND ints (counts, then scatter cursor)
    int*   curA   = curB + N_BND;        // N_ATM ints
    int*   posB   = curA + N_ATM;        // N_ANG ints (angle -> slot, encoder only)

    // dtype detection + conv params
    k_zero_int<<<1, 64, 0, stream>>>(flags, 64);
    k_detect<<<512, 256, 0, stream>>>(elg, (const unsigned*)mask, flags);
    k_cvt_any<<<30, 256, 0, stream>>>(convW, cw, 7680, flags);
    k_cvt_any<<<1, 256, 0, stream>>>(convB, cb, 192, flags);
    k_cvt_any<<<2, 256, 0, stream>>>(convLN, cln, 384, flags);

    // CSR: line graph (bonds <- angle edges)
    k_zero_int<<<N_BND / 256, 256, 0, stream>>>(curB, N_BND);
    k_count<<<N_ANG / 256, 256, 0, stream>>>(eiA + N_ANG, curB, N_ANG, N_BND);
    k_scan_local<<<N_BND / 256, 256, 0, stream>>>(curB, ofsB, bsum, N_BND);
    k_scan_bsum<<<1, 256, 0, stream>>>(bsum, N_BND / 256);
    k_scan_add2<<<N_BND / 256, 256, 0, stream>>>(ofsB, bsum, curB, N_BND, N_ANG);
    k_scatter_line2<<<N_ANG / 256, 256, 0, stream>>>(eiA, eiA + N_ANG, curB, srcB, posB,
                                                     N_ANG, N_BND);
    k_blkrange<<<(NB_L + 256) / 256, 256, 0, stream>>>(ofsB, N_BND, NB_L + 1, ownerL, firstL);

    // CSR: atom graph (atoms <- bond edges)
    k_zero_int<<<N_ATM / 256, 256, 0, stream>>>(curA, N_ATM);
    k_count<<<N_BND / 256, 256, 0, stream>>>(eiG + N_BND, curA, N_BND, N_ATM);
    k_scan_local<<<N_ATM / 256, 256, 0, stream>>>(curA, ofsA, bsum, N_ATM);
    k_scan_bsum<<<1, 256, 0, stream>>>(bsum, N_ATM / 256);
    k_scan_add2<<<N_ATM / 256, 256, 0, stream>>>(ofsA, bsum, curA, N_ATM, N_BND);
    k_scatter_atom2<<<N_BND / 256, 256, 0, stream>>>(eiG, eiG + N_BND, curA, srcG, eidG,
                                                     N_BND, N_ATM, N_ATM);
    k_blkrange<<<(NB_A + 256) / 256, 256, 0, stream>>>(ofsA, N_ATM, NB_A + 1, ownerA, firstA);

    // encoders (k_enc_ang consumes posB; bndB overlay dies here)
    k_enc_atm<<<N_ATM / 256, 256, 0, stream>>>(x_atm, eW1, eb1, eW2, eb2, elg, elb, flags, atmA);
    k_enc_bnd<<<N_BND / 256, 256, 0, stream>>>(x_bnd, eW1, eb1, eW2, eb2, elg, elb, flags, bndA);
    k_enc_ang<<<N_ANG / 256, 256, 0, stream>>>(x_ang, mask, eW1, eb1, eW2, eb2, elg, elb, flags,
                                               posB, angA);

    // processor: per round, bonds go A->B (line) then B->A (atom): valid bonds
    // are always in bndA at round start. Angles and atoms ping-pong per round.
    float* atmCur = atmA; float* atmOth = atmB;
    bf16*  angCur = angA; bf16*  angOth = angB;
    for (int c = 0; c < 3; c++) {
        const float* Wl = cw + (size_t)(c * 2 + 0) * 1280;
        const float* Bl = cb + (size_t)(c * 2 + 0) * 32;
        const float* Ll = cln + (size_t)(c * 2 + 0) * 64;
        k_fused<bf16, false><<<NB_L, NTHR, 0, stream>>>(
            bndA, bndB, angCur, angOth, srcB, (const int*)nullptr,
            ofsB, ownerL, firstL, Wl, Bl, Ll, N_ANG, N_BND, NB_L);
        const float* Wa = cw + (size_t)(c * 2 + 1) * 1280;
        const float* Ba = cb + (size_t)(c * 2 + 1) * 32;
        const float* La = cln + (size_t)(c * 2 + 1) * 64;
        k_fused<float, true><<<NB_A, NTHR, 0, stream>>>(
            atmCur, atmOth, bndB, bndA, srcG, eidG,
            ofsA, ownerA, firstA, Wa, Ba, La, N_BND, N_ATM, NB_A);
        float* ft = atmCur; atmCur = atmOth; atmOth = ft;
        bf16*  bt = angCur; angCur = angOth; angOth = bt;
    }

    k_pool2<<<N_GRAPHS, 256, 0, stream>>>(atmCur, batch, pooled);
    k_head<<<1, 256, 0, stream>>>(pooled, fp, l1W, l1b, l2W, l2b, flags, d_out);
}

// Round 7
// 3379.744 us; speedup vs baseline: 2.0346x; 1.2550x over previous
//
#include <hip/hip_runtime.h>
#include <hip/hip_bf16.h>

#define N_ATM 131072
#define N_BND 1048576
#define N_ANG 2097152
#define N_GRAPHS 256
#define PI_F 3.14159265358979323846f

#define FMAIN 192
#define FEXT 64
#define FWIN (FMAIN + FEXT)   // 256 slots per block window
#define NTHR 256              // 4-wave workgroup: one thread per window slot
#define NB_L ((N_ANG + FMAIN - 1) / FMAIN)   // 10923
#define NB_A ((N_BND + FMAIN - 1) / FMAIN)   // 5462

typedef __hip_bfloat16 bf16;

__device__ __forceinline__ int clampi(int v, int lo, int hi) {
    return v < lo ? lo : (v > hi ? hi : v);
}
__device__ __forceinline__ float b2f(bf16 v) { return __bfloat162float(v); }
__device__ __forceinline__ float sigmoidf_(float x) { return 1.0f / (1.0f + __expf(-x)); }
__device__ __forceinline__ float siluf_(float x) { return x / (1.0f + __expf(-x)); }

__device__ __forceinline__ float loadF(const void* p, long long i, int isbf) {
    return isbf ? b2f(((const bf16*)p)[i]) : ((const float*)p)[i];
}
__device__ __forceinline__ float bfbits2f(unsigned lo16) {
    union { unsigned u; float f; } c; c.u = lo16 << 16; return c.f;
}
__device__ __forceinline__ unsigned f2bfbits(float f) {
    union { float f; unsigned u; } c; c.f = f;
    unsigned u = c.u + 0x7FFFu + ((c.u >> 16) & 1u);  // RNE
    return u >> 16;
}

// ---- 16-wide row IO ----
__device__ __forceinline__ void load16f(const float* p, float* r) {
    const float4* q = (const float4*)p;
#pragma unroll
    for (int i = 0; i < 4; i++) { float4 v = q[i]; r[4*i]=v.x; r[4*i+1]=v.y; r[4*i+2]=v.z; r[4*i+3]=v.w; }
}
__device__ __forceinline__ void store16f(float* p, const float* r) {
    float4* q = (float4*)p;
#pragma unroll
    for (int i = 0; i < 4; i++) q[i] = make_float4(r[4*i], r[4*i+1], r[4*i+2], r[4*i+3]);
}
__device__ __forceinline__ void load16b(const bf16* p, float* r) {
    uint4 a = ((const uint4*)p)[0];
    uint4 b = ((const uint4*)p)[1];
    unsigned w[8] = {a.x, a.y, a.z, a.w, b.x, b.y, b.z, b.w};
#pragma unroll
    for (int i = 0; i < 8; i++) {
        r[2*i] = bfbits2f(w[i] & 0xFFFFu);
        union { unsigned u; float f; } c; c.u = w[i] & 0xFFFF0000u;
        r[2*i+1] = c.f;
    }
}
__device__ __forceinline__ void store16b(bf16* p, const float* r) {
    unsigned w[8];
#pragma unroll
    for (int i = 0; i < 8; i++)
        w[i] = f2bfbits(r[2*i]) | (f2bfbits(r[2*i+1]) << 16);
    ((uint4*)p)[0] = make_uint4(w[0], w[1], w[2], w[3]);
    ((uint4*)p)[1] = make_uint4(w[4], w[5], w[6], w[7]);
}

template <typename TX>
__device__ __forceinline__ void loadRow(const TX* p, float* r);
template <> __device__ __forceinline__ void loadRow<float>(const float* p, float* r) { load16f(p, r); }
template <> __device__ __forceinline__ void loadRow<bf16>(const bf16* p, float* r) { load16b(p, r); }
template <typename TX>
__device__ __forceinline__ void storeRow(TX* p, const float* r);
template <> __device__ __forceinline__ void storeRow<float>(float* p, const float* r) { store16f(p, r); }
template <> __device__ __forceinline__ void storeRow<bf16>(bf16* p, const float* r) { store16b(p, r); }

// ---------- utility ----------
__global__ void __launch_bounds__(256) k_zero_int(int* __restrict__ p, int n) {
    int i = blockIdx.x * 256 + threadIdx.x;
    if (i < n) p[i] = 0;
}

// flags[0]=1 if float tensors are bf16; flags[1]=1 if mask is byte-bools
__global__ void __launch_bounds__(256) k_detect(const void* lng, const unsigned* __restrict__ mask,
                                                int* flags) {
    int i = blockIdx.x * 256 + threadIdx.x;
    if (i == 0) flags[0] = (*(const unsigned*)lng == 0x3F803F80u) ? 1 : 0;
    int bad = 0;
    for (int j = i; j < 512 * 1024; j += 512 * 256)
        if (mask[j] > 1u) bad = 1;
    if (bad) atomicOr(&flags[1], 1);
}

__global__ void k_cvt_any(const void* __restrict__ src, float* __restrict__ dst, int n,
                          const int* __restrict__ flags) {
    int i = blockIdx.x * blockDim.x + threadIdx.x;
    if (i < n) dst[i] = loadF(src, i, flags[0]);
}

// ---------- CSR build ----------
__global__ void __launch_bounds__(256) k_count(const int* __restrict__ dst, int* __restrict__ cnt,
                                               int E, int n) {
    int i = blockIdx.x * 256 + threadIdx.x;
    if (i >= E) return;
    atomicAdd(&cnt[clampi(dst[i], 0, n - 1)], 1);
}
__global__ void __launch_bounds__(256) k_scan_local(const int* __restrict__ cnt, int* __restrict__ ofs,
                                                    int* __restrict__ bsum, int n) {
    __shared__ int s[256];
    int t = threadIdx.x, i = blockIdx.x * 256 + t;
    int v = (i < n) ? cnt[i] : 0;
    s[t] = v; __syncthreads();
    for (int o = 1; o < 256; o <<= 1) {
        int add = (t >= o) ? s[t - o] : 0;
        __syncthreads();
        s[t] += add;
        __syncthreads();
    }
    if (i < n) ofs[i] = s[t] - v;
    if (t == 255) bsum[blockIdx.x] = s[255];
}
__global__ void __launch_bounds__(256) k_scan_bsum(int* __restrict__ bsum, int nb) {
    __shared__ int s[256];
    __shared__ int run;
    int t = threadIdx.x;
    if (t == 0) run = 0;
    __syncthreads();
    for (int base = 0; base < nb; base += 256) {
        int i = base + t;
        int v = (i < nb) ? bsum[i] : 0;
        s[t] = v; __syncthreads();
        for (int o = 1; o < 256; o <<= 1) {
            int add = (t >= o) ? s[t - o] : 0;
            __syncthreads();
            s[t] += add;
            __syncthreads();
        }
        if (i < nb) bsum[i] = run + s[t] - v;
        __syncthreads();
        if (t == 0) run += s[255];
        __syncthreads();
    }
}
// finalizes ofs (adds block sums), copies cursor, writes sentinel ofs[n]=total
__global__ void __launch_bounds__(256) k_scan_add2(int* __restrict__ ofs, const int* __restrict__ bsum,
                                                   int* __restrict__ cursor, int n, int total) {
    int i = blockIdx.x * 256 + threadIdx.x;
    if (i < n) { int v = ofs[i] + bsum[blockIdx.x]; ofs[i] = v; cursor[i] = v; }
    if (i == 0) ofs[n] = total;
}
// line graph: permuted src + original->slot map (for angle encoder)
__global__ void __launch_bounds__(256) k_scatter_line2(
    const int* __restrict__ src, const int* __restrict__ dst, int* __restrict__ cur,
    int* __restrict__ srcP, int* __restrict__ pos, int E, int n)
{
    int i = blockIdx.x * 256 + threadIdx.x;
    if (i >= E) return;
    int d = clampi(dst[i], 0, n - 1);
    int s = clampi(src[i], 0, n - 1);
    int p = clampi(atomicAdd(&cur[d], 1), 0, E - 1);
    srcP[p] = s; pos[i] = p;
}
// atom graph: permuted src + original bond id per slot
__global__ void __launch_bounds__(256) k_scatter_atom2(
    const int* __restrict__ src, const int* __restrict__ dst, int* __restrict__ cur,
    int* __restrict__ srcP, int* __restrict__ eidP, int E, int n, int ns)
{
    int i = blockIdx.x * 256 + threadIdx.x;
    if (i >= E) return;
    int d = clampi(dst[i], 0, n - 1);
    int s = clampi(src[i], 0, ns - 1);
    int p = clampi(atomicAdd(&cur[d], 1), 0, E - 1);
    srcP[p] = s; eidP[p] = i;
}
// per-block-boundary node ranges (CSR static across rounds -> compute once)
// owner[b] = last d with ofs[d] <= b*FMAIN ; first[b] = first d with ofs[d] >= b*FMAIN
__global__ void __launch_bounds__(256) k_blkrange(const int* __restrict__ ofs, int N, int nbp1,
                                                  int* __restrict__ owner, int* __restrict__ first) {
    int b = blockIdx.x * 256 + threadIdx.x;
    if (b >= nbp1) return;
    int B0 = b * FMAIN;
    int lo = 0, hi = N;
    while (lo < hi) { int m = (lo + hi) >> 1; if (ofs[m] < B0) lo = m + 1; else hi = m; }
    first[b] = lo;
    lo = 0; hi = N + 1;
    while (lo < hi) { int m = (lo + hi) >> 1; if (ofs[m] <= B0) lo = m + 1; else hi = m; }
    owner[b] = (lo - 1) < 0 ? 0 : (lo - 1);
}

// ---------- encoders ----------
__global__ void __launch_bounds__(256) k_enc_atm(
    const int* __restrict__ sp_in,
    const void* W1, const void* b1, const void* W2, const void* b2,
    const void* g, const void* be, const int* __restrict__ flags,
    float* __restrict__ out)
{
    __shared__ float sW1[256], sW2[256], sb1[16], sb2[16], sg[16], sbe[16];
    int t = threadIdx.x, isbf = flags[0];
    sW1[t] = loadF(W1, t, isbf); sW2[t] = loadF(W2, t, isbf);
    if (t < 16) { sb1[t]=loadF(b1,t,isbf); sb2[t]=loadF(b2,t,isbf); sg[t]=loadF(g,t,isbf); sbe[t]=loadF(be,t,isbf); }
    __syncthreads();
    int i = blockIdx.x * 256 + t;
    if (i >= N_ATM) return;
    int sp = clampi(sp_in[i], 0, 15);
    float h[16];
#pragma unroll
    for (int j = 0; j < 16; j++) h[j] = siluf_(sW1[sp * 16 + j] + sb1[j]);
    float o[16]; float mu = 0.f;
#pragma unroll
    for (int j = 0; j < 16; j++) {
        float a = sb2[j];
#pragma unroll
        for (int k = 0; k < 16; k++) a += h[k] * sW2[k * 16 + j];
        o[j] = a; mu += a;
    }
    mu *= (1.f / 16.f);
    float var = 0.f;
#pragma unroll
    for (int j = 0; j < 16; j++) { float d = o[j] - mu; var += d * d; }
    var *= (1.f / 16.f);
    float r = rsqrtf(var + 1e-5f);
    float ov[16];
#pragma unroll
    for (int j = 0; j < 16; j++) ov[j] = (o[j] - mu) * r * sg[j] + sbe[j];
    store16f(out + (long long)i * 16, ov);
}

__global__ void __launch_bounds__(256) k_enc_bnd(
    const void* __restrict__ xb,
    const void* W1, const void* b1, const void* W2, const void* b2,
    const void* g, const void* be, const int* __restrict__ flags,
    bf16* __restrict__ out)
{
    __shared__ float sW1[256], sW2[256], sb1[16], sb2[16], sg[16], sbe[16];
    int t = threadIdx.x, isbf = flags[0];
    sW1[t] = loadF(W1, 256 + t, isbf); sW2[t] = loadF(W2, 256 + t, isbf);
    if (t < 16) { sb1[t]=loadF(b1,16+t,isbf); sb2[t]=loadF(b2,16+t,isbf); sg[t]=loadF(g,16+t,isbf); sbe[t]=loadF(be,16+t,isbf); }
    __syncthreads();
    int i = blockIdx.x * 256 + t;
    if (i >= N_BND) return;
    float x = loadF(xb, i, isbf) + 1e-5f;
    const float c = 0.6324555320336759f; // sqrt(2/5)
    float inv = c / x;
    float feat[16];
#pragma unroll
    for (int k = 0; k < 16; k++) feat[k] = __sinf((float)(k + 1) * PI_F * x * 0.2f) * inv;
    float h[16];
#pragma unroll
    for (int j = 0; j < 16; j++) {
        float a = sb1[j];
#pragma unroll
        for (int k = 0; k < 16; k++) a += feat[k] * sW1[k * 16 + j];
        h[j] = siluf_(a);
    }
    float o[16]; float mu = 0.f;
#pragma unroll
    for (int j = 0; j < 16; j++) {
        float a = sb2[j];
#pragma unroll
        for (int k = 0; k < 16; k++) a += h[k] * sW2[k * 16 + j];
        o[j] = a; mu += a;
    }
    mu *= (1.f / 16.f);
    float var = 0.f;
#pragma unroll
    for (int j = 0; j < 16; j++) { float d = o[j] - mu; var += d * d; }
    var *= (1.f / 16.f);
    float r = rsqrtf(var + 1e-5f);
    float ov[16];
#pragma unroll
    for (int j = 0; j < 16; j++) ov[j] = (o[j] - mu) * r * sg[j] + sbe[j];
    store16b(out + (long long)i * 16, ov);
}

// angle encoder: writes row to CSR slot pos[i]
__global__ void __launch_bounds__(256) k_enc_ang(
    const void* __restrict__ xa, const void* __restrict__ mask,
    const void* W1, const void* b1, const void* W2, const void* b2,
    const void* g, const void* be, const int* __restrict__ flags,
    const int* __restrict__ pos, bf16* __restrict__ out)
{
    __shared__ float sW1[512], sW2[512], sb1[32], sb2[32], sg[32], sbe[32];
    int t = threadIdx.x, isbf = flags[0], mbyte = flags[1];
    for (int i = t; i < 512; i += 256) { sW1[i] = loadF(W1, 512 + i, isbf); sW2[i] = loadF(W2, 512 + i, isbf); }
    if (t < 32) { sb1[t]=loadF(b1,32+t,isbf); sb2[t]=loadF(b2,32+t,isbf); sg[t]=loadF(g,32+t,isbf); sbe[t]=loadF(be,32+t,isbf); }
    __syncthreads();
    int i = blockIdx.x * 256 + t;
    if (i >= N_ANG) return;
    int m = mbyte ? (((const unsigned char*)mask)[i] != 0) : (((const int*)mask)[i] != 0);
    float x = loadF(xa, i, isbf);
    float gam = m ? 2.3873241463784303f : 4.7746482927568605f;   // 15/(2pi) : 15/pi
    float c0  = m ? -PI_F : 0.0f;
    float dc  = m ? 0.41887902047863906f : 0.20943951023931953f; // 2pi/15 : pi/15
    int wo = m * 256, vo = m * 16;
    float feat[16];
#pragma unroll
    for (int k = 0; k < 16; k++) {
        float d = gam * (x - (c0 + (float)k * dc));
        feat[k] = __expf(-d * d);
    }
    float h[16];
#pragma unroll
    for (int j = 0; j < 16; j++) {
        float a = sb1[vo + j];
#pragma unroll
        for (int k = 0; k < 16; k++) a += feat[k] * sW1[wo + k * 16 + j];
        h[j] = siluf_(a);
    }
    float o[16]; float mu = 0.f;
#pragma unroll
    for (int j = 0; j < 16; j++) {
        float a = sb2[vo + j];
#pragma unroll
        for (int k = 0; k < 16; k++) a += h[k] * sW2[wo + k * 16 + j];
        o[j] = a; mu += a;
    }
    mu *= (1.f / 16.f);
    float var = 0.f;
#pragma unroll
    for (int j = 0; j < 16; j++) { float d = o[j] - mu; var += d * d; }
    var *= (1.f / 16.f);
    float r = rsqrtf(var + 1e-5f);
    float ov[16];
#pragma unroll
    for (int j = 0; j < 16; j++) ov[j] = (o[j] - mu) * r * sg[vo + j] + sbe[vo + j];
    store16b(out + (long long)clampi(pos[i], 0, N_ANG - 1) * 16, ov);
}

// ---------- fused edge+node conv ----------
// Block b owns CSR slots [b*192, b*192+192); 256 threads (4 waves -> the allocator's
// 3-waves/SIMD budget ~170 VGPR, vs 128 for 5-wave blocks: the R3-R6 spill source)
// cover main + <=64 extension slots. Overlapping windows recompute extension edges
// (~33% redundant edge work) - cheaper than any scratch round-trip.
// (msg,sigma) staged in LDS as 4x uint4 per slot, slot stride 5 (pad -> banks spread).
// e fully ping-ponged (Ein read-only) so extension reads never race e_new writes.
// VIA_EID: e rows accessed through eid[] (atom graph: bonds stored in natural order).
// Node phase: all d with ofs[d] in [B0, B0+192); last block absorbs the tail + deg-0
// nodes (num=den=0 -> matches reference). Tail blocks: mainLen = min(FMAIN, E-B0).
// Register-diet body (R6): multi-pass edge math, lean node loop, direct LDS indexing.
template <typename TX, bool VIA_EID>
__global__ void __launch_bounds__(NTHR) k_fused(
    const TX* __restrict__ X, TX* __restrict__ Xn,
    const bf16* __restrict__ Ein, bf16* __restrict__ Eout,
    const int* __restrict__ src, const int* __restrict__ eid,
    const int* __restrict__ ofs, const int* __restrict__ owner, const int* __restrict__ first,
    const float* __restrict__ W, const float* __restrict__ Bp, const float* __restrict__ L,
    int E, int N, int nb)
{
    __shared__ float sW[1280], sB[32], sLg[32], sLb[32];
    __shared__ uint4 sMS4[FWIN * 5];   // slot w -> sMS4[w*5 .. w*5+3], +1 pad
    __shared__ int sDst[FWIN];
    int t = threadIdx.x;
    int b = blockIdx.x;
    int B0 = b * FMAIN;
    for (int i = t; i < 1280; i += NTHR) sW[i] = W[i];
    if (t < 16) {
        sB[t] = Bp[t];        sB[16 + t] = Bp[16 + t];
        sLg[t] = L[32 + t];   sLb[t] = L[48 + t];       // edge LN
        sLg[16 + t] = L[t];   sLb[16 + t] = L[16 + t];  // node LN
    }
    int d0      = owner[b];
    int dNodeLo = first[b];
    int dhi     = first[b + 1];
    int dhiN    = (b == nb - 1) ? N : dhi;
    // fill slot -> dst map for the window
    for (int dd = d0 + t; dd < dhi; dd += NTHR) {
        int a = ofs[dd], e2 = ofs[dd + 1];
        int lo2 = a < B0 ? B0 : a;
        int hi2 = e2 > B0 + FWIN ? B0 + FWIN : e2;
        for (int p = lo2; p < hi2; p++) sDst[p - B0] = dd;
    }
    __syncthreads();
    // ---- edge phase: one slot per thread, multi-pass (minimal liveness) ----
    int mainLen = E - B0; if (mainLen > FMAIN) mainLen = FMAIN;   // >0 always
    int eExt = ofs[clampi(dhi, 0, N)] - (B0 + FMAIN);
    eExt = eExt < 0 ? 0 : (eExt > FEXT ? FEXT : eExt);            // 0 for tail blocks
    bool act = (t < FMAIN) ? (t < mainLen) : (t < FMAIN + eExt);
    if (act) {
        int p = B0 + t;
        long long erow = VIA_EID ? (long long)clampi(eid[p], 0, E - 1) : (long long)p;
        float z[16], mm[16];
        // pass 1: xs -> mm and z  (xs dies after)
        {
            float xs[16];
            {
                int s = clampi(src[p], 0, N - 1);
                loadRow<TX>(X + (long long)s * 16, xs);
            }
#pragma unroll
            for (int j = 0; j < 16; j++) { mm[j] = 0.f; z[j] = sB[j]; }
#pragma unroll
            for (int k = 0; k < 16; k++) {
                float a = xs[k];
#pragma unroll
                for (int j = 0; j < 16; j++) {
                    mm[j] += a * sW[1024 + k * 16 + j];
                    z[j]  += a * sW[k * 16 + j];
                }
            }
        }
        // pass 2: xd -> z  (xd dies after)
        {
            float xd[16];
            {
                int d = clampi(sDst[t], 0, N - 1);
                loadRow<TX>(X + (long long)d * 16, xd);
            }
#pragma unroll
            for (int k = 0; k < 16; k++) {
                float a = xd[k];
#pragma unroll
                for (int j = 0; j < 16; j++) z[j] += a * sW[256 + k * 16 + j];
            }
        }
        // pass 3: ev -> z  (ev stays live for the residual)
        float ev[16];
        load16b(Ein + erow * 16, ev);
#pragma unroll
        for (int k = 0; k < 16; k++) {
            float a = ev[k];
#pragma unroll
            for (int j = 0; j < 16; j++) z[j] += a * sW[512 + k * 16 + j];
        }
        // pack (sigma*mm, sigma) -> LDS directly  (mm dies)
        {
            unsigned pm[8], ps[8];
#pragma unroll
            for (int i = 0; i < 8; i++) {
                float a0 = sigmoidf_(z[2*i]);
                float a1 = sigmoidf_(z[2*i+1]);
                pm[i] = f2bfbits(a0 * mm[2*i]) | (f2bfbits(a1 * mm[2*i+1]) << 16);
                ps[i] = f2bfbits(a0)           | (f2bfbits(a1) << 16);
            }
            sMS4[t * 5 + 0] = make_uint4(pm[0], pm[1], pm[2], pm[3]);
            sMS4[t * 5 + 1] = make_uint4(pm[4], pm[5], pm[6], pm[7]);
            sMS4[t * 5 + 2] = make_uint4(ps[0], ps[1], ps[2], ps[3]);
            sMS4[t * 5 + 3] = make_uint4(ps[4], ps[5], ps[6], ps[7]);
        }
        // LN + residual -> Eout (only main slots write)
        if (t < mainLen) {
            float mu = 0.f;
#pragma unroll
            for (int j = 0; j < 16; j++) mu += z[j];
            mu *= (1.f / 16.f);
            float var = 0.f;
#pragma unroll
            for (int j = 0; j < 16; j++) { float dd = z[j] - mu; var += dd * dd; }
            var *= (1.f / 16.f);
            float r = rsqrtf(var + 1e-5f);
            float eo[16];
#pragma unroll
            for (int j = 0; j < 16; j++)
                eo[j] = ev[j] + siluf_((z[j] - mu) * r * sLg[j] + sLb[j]);
            store16b(Eout + erow * 16, eo);
        }
    }
    __syncthreads();
    // ---- node phase (lean loop: only num/den live across the backedge) ----
    for (int d = dNodeLo + t; d < dhiN; d += NTHR) {
        float num[16], den[16];
#pragma unroll
        for (int j = 0; j < 16; j++) { num[j] = 0.f; den[j] = 0.f; }
        int p0 = ofs[d], p1 = ofs[d + 1];
        for (int p = p0; p < p1; p++) {
            int q5 = clampi(p - B0, 0, FWIN - 1) * 5;
            {
                uint4 q0 = sMS4[q5 + 0];
                num[0] += bfbits2f(q0.x & 0xFFFFu); num[1] += bfbits2f(q0.x >> 16);
                num[2] += bfbits2f(q0.y & 0xFFFFu); num[3] += bfbits2f(q0.y >> 16);
                num[4] += bfbits2f(q0.z & 0xFFFFu); num[5] += bfbits2f(q0.z >> 16);
                num[6] += bfbits2f(q0.w & 0xFFFFu); num[7] += bfbits2f(q0.w >> 16);
            }
            {
                uint4 q1 = sMS4[q5 + 1];
                num[8]  += bfbits2f(q1.x & 0xFFFFu); num[9]  += bfbits2f(q1.x >> 16);
                num[10] += bfbits2f(q1.y & 0xFFFFu); num[11] += bfbits2f(q1.y >> 16);
                num[12] += bfbits2f(q1.z & 0xFFFFu); num[13] += bfbits2f(q1.z >> 16);
                num[14] += bfbits2f(q1.w & 0xFFFFu); num[15] += bfbits2f(q1.w >> 16);
            }
            {
                uint4 q2 = sMS4[q5 + 2];
                den[0] += bfbits2f(q2.x & 0xFFFFu); den[1] += bfbits2f(q2.x >> 16);
                den[2] += bfbits2f(q2.y & 0xFFFFu); den[3] += bfbits2f(q2.y >> 16);
                den[4] += bfbits2f(q2.z & 0xFFFFu); den[5] += bfbits2f(q2.z >> 16);
                den[6] += bfbits2f(q2.w & 0xFFFFu); den[7] += bfbits2f(q2.w >> 16);
            }
            {
                uint4 q3 = sMS4[q5 + 3];
                den[8]  += bfbits2f(q3.x & 0xFFFFu); den[9]  += bfbits2f(q3.x >> 16);
                den[10] += bfbits2f(q3.y & 0xFFFFu); den[11] += bfbits2f(q3.y >> 16);
                den[12] += bfbits2f(q3.z & 0xFFFFu); den[13] += bfbits2f(q3.z >> 16);
                den[14] += bfbits2f(q3.w & 0xFFFFu); den[15] += bfbits2f(q3.w >> 16);
            }
        }
        // fold num/den, then bring in xv (NOT live during the loop above)
        float xv[16];
        loadRow<TX>(X + (long long)d * 16, xv);
        float tt[16]; float mu = 0.f;
#pragma unroll
        for (int j = 0; j < 16; j++) {
            float a = sB[16 + j] + num[j] / (den[j] + 1e-5f);
#pragma unroll
            for (int k = 0; k < 16; k++) a += xv[k] * sW[768 + k * 16 + j];
            tt[j] = a; mu += a;
        }
        mu *= (1.f / 16.f);
        float var = 0.f;
#pragma unroll
        for (int j = 0; j < 16; j++) { float dd2 = tt[j] - mu; var += dd2 * dd2; }
        var *= (1.f / 16.f);
        float r = rsqrtf(var + 1e-5f);
        float ov[16];
#pragma unroll
        for (int j = 0; j < 16; j++)
            ov[j] = xv[j] + siluf_((tt[j] - mu) * r * sLg[16 + j] + sLb[16 + j]);
        storeRow<TX>(Xn + (long long)d * 16, ov);
    }
}

// ---------- pooling: one block per graph (batch sorted, no atomics) ----------
__global__ void __launch_bounds__(256) k_pool2(
    const float* __restrict__ h, const int* __restrict__ batch, float* __restrict__ pooled)
{
    int g = blockIdx.x;
    int lo = 0, hi = N_ATM;
    while (lo < hi) { int m = (lo + hi) >> 1; if (batch[m] < g) lo = m + 1; else hi = m; }
    int s0 = lo;
    lo = 0; hi = N_ATM;
    while (lo < hi) { int m = (lo + hi) >> 1; if (batch[m] < g + 1) lo = m + 1; else hi = m; }
    int s1 = lo;
    float acc[16];
#pragma unroll
    for (int j = 0; j < 16; j++) acc[j] = 0.f;
    for (int i = s0 + threadIdx.x; i < s1; i += 256) {
        float v[16];
        load16f(h + (long long)i * 16, v);
#pragma unroll
        for (int j = 0; j < 16; j++) acc[j] += v[j];
    }
#pragma unroll
    for (int j = 0; j < 16; j++)
        for (int o = 32; o > 0; o >>= 1) acc[j] += __shfl_down(acc[j], o, 64);
    __shared__ float red[4][16];
    int wv = threadIdx.x >> 6, ln = threadIdx.x & 63;
    if (ln == 0)
#pragma unroll
        for (int j = 0; j < 16; j++) red[wv][j] = acc[j];
    __syncthreads();
    if (threadIdx.x < 16)
        pooled[g * 16 + threadIdx.x] = red[0][threadIdx.x] + red[1][threadIdx.x]
                                     + red[2][threadIdx.x] + red[3][threadIdx.x];
}

// ---------- head ----------
__global__ void __launch_bounds__(256) k_head(
    const float* __restrict__ pooled, const void* __restrict__ fp,
    const void* l1W, const void* l1b, const void* l2W, const void* l2b,
    const int* __restrict__ flags, void* __restrict__ out)
{
    __shared__ float sW[18 * 16], sb[16], s2W[16];
    int t = threadIdx.x, isbf = flags[0];
    for (int i = t; i < 288; i += 256) sW[i] = loadF(l1W, i, isbf);
    if (t < 16) { sb[t] = loadF(l1b, t, isbf); s2W[t] = loadF(l2W, t, isbf); }
    __syncthreads();
    int g = t;
    if (g >= N_GRAPHS) return;
    float in[18];
#pragma unroll
    for (int j = 0; j < 16; j++) in[j] = pooled[g * 16 + j];
    in[16] = loadF(fp, 2 * g, isbf);
    in[17] = loadF(fp, 2 * g + 1, isbf);
    float acc = loadF(l2b, 0, isbf);
#pragma unroll
    for (int j = 0; j < 16; j++) {
        float h = sb[j];
#pragma unroll
        for (int k = 0; k < 18; k++) h += in[k] * sW[k * 16 + j];
        h = (h > 0.f) ? h : 0.01f * h;
        acc += h * s2W[j];
    }
    if (isbf) ((bf16*)out)[g] = __float2bfloat16(acc);
    else      ((float*)out)[g] = acc;
}

extern "C" void kernel_launch(void* const* d_in, const int* in_sizes, int n_in,
                              void* d_out, int out_size, void* d_ws, size_t ws_size,
                              hipStream_t stream) {
    const int*  x_atm = (const int*)d_in[0];
    const void* x_bnd = d_in[1];
    const void* x_ang = d_in[2];
    const void* mask  = d_in[3];
    const int*  eiG   = (const int*)d_in[4];
    const int*  eiA   = (const int*)d_in[5];
    const int*  batch = (const int*)d_in[6];
    const void* fp    = d_in[7];
    const void* eW1 = d_in[8],  *eb1 = d_in[9],  *eW2 = d_in[10], *eb2 = d_in[11];
    const void* elg = d_in[12], *elb = d_in[13];
    const void* convW = d_in[14], *convB = d_in[15], *convLN = d_in[16];
    const void* l1W = d_in[17], *l1b = d_in[18], *l2W = d_in[19], *l2b = d_in[20];

    // Workspace layout — total ~239.8 MB (< proven-safe 241.2 MB)
    char* p = (char*)d_ws;
    int*   flags  = (int*)p;   p += 256;
    float* cw     = (float*)p; p += 7680 * 4;
    float* cb     = (float*)p; p += 192 * 4;
    float* cln    = (float*)p; p += 384 * 4;
    float* pooled = (float*)p; p += 4096 * 4;
    int*   bsum   = (int*)p;   p += 4096 * 4;
    int*   ownerL = (int*)p;   p += 11008 * 4;  // NB_L+1 = 10924 used
    int*   firstL = (int*)p;   p += 11008 * 4;
    int*   ownerA = (int*)p;   p += 5632 * 4;   // NB_A+1 = 5463 used
    int*   firstA = (int*)p;   p += 5632 * 4;
    int*   ofsB   = (int*)p;   p += (size_t)(N_BND + 256) * 4;  // +sentinel
    int*   srcB   = (int*)p;   p += (size_t)N_ANG * 4;
    int*   ofsA   = (int*)p;   p += (size_t)(N_ATM + 256) * 4;  // +sentinel
    int*   srcG   = (int*)p;   p += (size_t)N_BND * 4;
    int*   eidG   = (int*)p;   p += (size_t)N_BND * 4;
    float* atmA   = (float*)p; p += (size_t)N_ATM * 64;
    float* atmB   = (float*)p; p += (size_t)N_ATM * 64;
    bf16*  bndA   = (bf16*)p;  p += (size_t)N_BND * 32;
    bf16*  bndB   = (bf16*)p;  p += (size_t)N_BND * 32;
    bf16*  angA   = (bf16*)p;  p += (size_t)N_ANG * 32;
    bf16*  angB   = (bf16*)p;
    // overlay: cursors + angle slot map live in bndB, which is first written in
    // round-1 line node phase (long after CSR build + encoders are done)
    int*   curB   = (int*)bndB;          // N_BND ints (counts, then scatter cursor)
    int*   curA   = curB + N_BND;        // N_ATM ints
    int*   posB   = curA + N_ATM;        // N_ANG ints (angle -> slot, encoder only)

    // dtype detection + conv params
    k_zero_int<<<1, 64, 0, stream>>>(flags, 64);
    k_detect<<<512, 256, 0, stream>>>(elg, (const unsigned*)mask, flags);
    k_cvt_any<<<30, 256, 0, stream>>>(convW, cw, 7680, flags);
    k_cvt_any<<<1, 256, 0, stream>>>(convB, cb, 192, flags);
    k_cvt_any<<<2, 256, 0, stream>>>(convLN, cln, 384, flags);

    // CSR: line graph (bonds <- angle edges)
    k_zero_int<<<N_BND / 256, 256, 0, stream>>>(curB, N_BND);
    k_count<<<N_ANG / 256, 256, 0, stream>>>(eiA + N_ANG, curB, N_ANG, N_BND);
    k_scan_local<<<N_BND / 256, 256, 0, stream>>>(curB, ofsB, bsum, N_BND);
    k_scan_bsum<<<1, 256, 0, stream>>>(bsum, N_BND / 256);
    k_scan_add2<<<N_BND / 256, 256, 0, stream>>>(ofsB, bsum, curB, N_BND, N_ANG);
    k_scatter_line2<<<N_ANG / 256, 256, 0, stream>>>(eiA, eiA + N_ANG, curB, srcB, posB,
                                                     N_ANG, N_BND);
    k_blkrange<<<((NB_L + 1) + 255) / 256, 256, 0, stream>>>(ofsB, N_BND, NB_L + 1, ownerL, firstL);

    // CSR: atom graph (atoms <- bond edges)
    k_zero_int<<<N_ATM / 256, 256, 0, stream>>>(curA, N_ATM);
    k_count<<<N_BND / 256, 256, 0, stream>>>(eiG + N_BND, curA, N_BND, N_ATM);
    k_scan_local<<<N_ATM / 256, 256, 0, stream>>>(curA, ofsA, bsum, N_ATM);
    k_scan_bsum<<<1, 256, 0, stream>>>(bsum, N_ATM / 256);
    k_scan_add2<<<N_ATM / 256, 256, 0, stream>>>(ofsA, bsum, curA, N_ATM, N_BND);
    k_scatter_atom2<<<N_BND / 256, 256, 0, stream>>>(eiG, eiG + N_BND, curA, srcG, eidG,
                                                     N_BND, N_ATM, N_ATM);
    k_blkrange<<<((NB_A + 1) + 255) / 256, 256, 0, stream>>>(ofsA, N_ATM, NB_A + 1, ownerA, firstA);

    // encoders (k_enc_ang consumes posB; bndB overlay dies here)
    k_enc_atm<<<N_ATM / 256, 256, 0, stream>>>(x_atm, eW1, eb1, eW2, eb2, elg, elb, flags, atmA);
    k_enc_bnd<<<N_BND / 256, 256, 0, stream>>>(x_bnd, eW1, eb1, eW2, eb2, elg, elb, flags, bndA);
    k_enc_ang<<<N_ANG / 256, 256, 0, stream>>>(x_ang, mask, eW1, eb1, eW2, eb2, elg, elb, flags,
                                               posB, angA);

    // processor: per round, bonds go A->B (line) then B->A (atom): valid bonds
    // are always in bndA at round start. Angles and atoms ping-pong per round.
    float* atmCur = atmA; float* atmOth = atmB;
    bf16*  angCur = angA; bf16*  angOth = angB;
    for (int c = 0; c < 3; c++) {
        const float* Wl = cw + (size_t)(c * 2 + 0) * 1280;
        const float* Bl = cb + (size_t)(c * 2 + 0) * 32;
        const float* Ll = cln + (size_t)(c * 2 + 0) * 64;
        k_fused<bf16, false><<<NB_L, NTHR, 0, stream>>>(
            bndA, bndB, angCur, angOth, srcB, (const int*)nullptr,
            ofsB, ownerL, firstL, Wl, Bl, Ll, N_ANG, N_BND, NB_L);
        const float* Wa = cw + (size_t)(c * 2 + 1) * 1280;
        const float* Ba = cb + (size_t)(c * 2 + 1) * 32;
        const float* La = cln + (size_t)(c * 2 + 1) * 64;
        k_fused<float, true><<<NB_A, NTHR, 0, stream>>>(
            atmCur, atmOth, bndB, bndA, srcG, eidG,
            ofsA, ownerA, firstA, Wa, Ba, La, N_BND, N_ATM, NB_A);
        float* ft = atmCur; atmCur = atmOth; atmOth = ft;
        bf16*  bt = angCur; angCur = angOth; angOth = bt;
    }

    k_pool2<<<N_GRAPHS, 256, 0, stream>>>(atmCur, batch, pooled);
    k_head<<<1, 256, 0, stream>>>(pooled, fp, l1W, l1b, l2W, l2b, flags, d_out);
}

// Round 8
// 3375.080 us; speedup vs baseline: 2.0374x; 1.0014x over previous
//
#include <hip/hip_runtime.h>
#include <hip/hip_bf16.h>

#define N_ATM 131072
#define N_BND 1048576
#define N_ANG 2097152
#define N_GRAPHS 256
#define PI_F 3.14159265358979323846f

#define FMAIN 192
#define FEXT 64
#define FWIN (FMAIN + FEXT)   // 256 slots per block window
#define NTHR 256              // 4-wave workgroup: one thread per window slot
#define NB_L ((N_ANG + FMAIN - 1) / FMAIN)   // 10923
#define NB_A ((N_BND + FMAIN - 1) / FMAIN)   // 5462

typedef __hip_bfloat16 bf16;

__device__ __forceinline__ int clampi(int v, int lo, int hi) {
    return v < lo ? lo : (v > hi ? hi : v);
}
__device__ __forceinline__ float b2f(bf16 v) { return __bfloat162float(v); }
__device__ __forceinline__ float sigmoidf_(float x) { return 1.0f / (1.0f + __expf(-x)); }
__device__ __forceinline__ float siluf_(float x) { return x / (1.0f + __expf(-x)); }

__device__ __forceinline__ float loadF(const void* p, long long i, int isbf) {
    return isbf ? b2f(((const bf16*)p)[i]) : ((const float*)p)[i];
}
__device__ __forceinline__ float bfbits2f(unsigned lo16) {
    union { unsigned u; float f; } c; c.u = lo16 << 16; return c.f;
}
__device__ __forceinline__ unsigned f2bfbits(float f) {
    union { float f; unsigned u; } c; c.f = f;
    unsigned u = c.u + 0x7FFFu + ((c.u >> 16) & 1u);  // RNE
    return u >> 16;
}

// ---- 16-wide row IO ----
__device__ __forceinline__ void load16f(const float* p, float* r) {
    const float4* q = (const float4*)p;
#pragma unroll
    for (int i = 0; i < 4; i++) { float4 v = q[i]; r[4*i]=v.x; r[4*i+1]=v.y; r[4*i+2]=v.z; r[4*i+3]=v.w; }
}
__device__ __forceinline__ void store16f(float* p, const float* r) {
    float4* q = (float4*)p;
#pragma unroll
    for (int i = 0; i < 4; i++) q[i] = make_float4(r[4*i], r[4*i+1], r[4*i+2], r[4*i+3]);
}
__device__ __forceinline__ void load16b(const bf16* p, float* r) {
    uint4 a = ((const uint4*)p)[0];
    uint4 b = ((const uint4*)p)[1];
    unsigned w[8] = {a.x, a.y, a.z, a.w, b.x, b.y, b.z, b.w};
#pragma unroll
    for (int i = 0; i < 8; i++) {
        r[2*i] = bfbits2f(w[i] & 0xFFFFu);
        union { unsigned u; float f; } c; c.u = w[i] & 0xFFFF0000u;
        r[2*i+1] = c.f;
    }
}
__device__ __forceinline__ void store16b(bf16* p, const float* r) {
    unsigned w[8];
#pragma unroll
    for (int i = 0; i < 8; i++)
        w[i] = f2bfbits(r[2*i]) | (f2bfbits(r[2*i+1]) << 16);
    ((uint4*)p)[0] = make_uint4(w[0], w[1], w[2], w[3]);
    ((uint4*)p)[1] = make_uint4(w[4], w[5], w[6], w[7]);
}

template <typename TX>
__device__ __forceinline__ void loadRow(const TX* p, float* r);
template <> __device__ __forceinline__ void loadRow<float>(const float* p, float* r) { load16f(p, r); }
template <> __device__ __forceinline__ void loadRow<bf16>(const bf16* p, float* r) { load16b(p, r); }
template <typename TX>
__device__ __forceinline__ void storeRow(TX* p, const float* r);
template <> __device__ __forceinline__ void storeRow<float>(float* p, const float* r) { store16f(p, r); }
template <> __device__ __forceinline__ void storeRow<bf16>(bf16* p, const float* r) { store16b(p, r); }

// ---- raw-staged row loads: issue early (in flight), unpack late ----
template <typename TX> struct Stage;
template <> struct Stage<bf16> {
    uint4 a, b;
    __device__ __forceinline__ void issue(const bf16* p) {
        a = ((const uint4*)p)[0]; b = ((const uint4*)p)[1];
    }
    __device__ __forceinline__ void unpack(float* r) const {
        unsigned w[8] = {a.x, a.y, a.z, a.w, b.x, b.y, b.z, b.w};
#pragma unroll
        for (int i = 0; i < 8; i++) {
            r[2*i] = bfbits2f(w[i] & 0xFFFFu);
            union { unsigned u; float f; } c; c.u = w[i] & 0xFFFF0000u;
            r[2*i+1] = c.f;
        }
    }
};
template <> struct Stage<float> {
    float4 a, b, c, d;
    __device__ __forceinline__ void issue(const float* p) {
        const float4* q = (const float4*)p; a = q[0]; b = q[1]; c = q[2]; d = q[3];
    }
    __device__ __forceinline__ void unpack(float* r) const {
        r[0]=a.x; r[1]=a.y; r[2]=a.z; r[3]=a.w;
        r[4]=b.x; r[5]=b.y; r[6]=b.z; r[7]=b.w;
        r[8]=c.x; r[9]=c.y; r[10]=c.z; r[11]=c.w;
        r[12]=d.x; r[13]=d.y; r[14]=d.z; r[15]=d.w;
    }
};

// ---------- utility ----------
__global__ void __launch_bounds__(256) k_zero_int(int* __restrict__ p, int n) {
    int i = blockIdx.x * 256 + threadIdx.x;
    if (i < n) p[i] = 0;
}

// flags[0]=1 if float tensors are bf16; flags[1]=1 if mask is byte-bools
__global__ void __launch_bounds__(256) k_detect(const void* lng, const unsigned* __restrict__ mask,
                                                int* flags) {
    int i = blockIdx.x * 256 + threadIdx.x;
    if (i == 0) flags[0] = (*(const unsigned*)lng == 0x3F803F80u) ? 1 : 0;
    int bad = 0;
    for (int j = i; j < 512 * 1024; j += 512 * 256)
        if (mask[j] > 1u) bad = 1;
    if (bad) atomicOr(&flags[1], 1);
}

__global__ void k_cvt_any(const void* __restrict__ src, float* __restrict__ dst, int n,
                          const int* __restrict__ flags) {
    int i = blockIdx.x * blockDim.x + threadIdx.x;
    if (i < n) dst[i] = loadF(src, i, flags[0]);
}

// ---------- CSR build ----------
__global__ void __launch_bounds__(256) k_count(const int* __restrict__ dst, int* __restrict__ cnt,
                                               int E, int n) {
    int i = blockIdx.x * 256 + threadIdx.x;
    if (i >= E) return;
    atomicAdd(&cnt[clampi(dst[i], 0, n - 1)], 1);
}
__global__ void __launch_bounds__(256) k_scan_local(const int* __restrict__ cnt, int* __restrict__ ofs,
                                                    int* __restrict__ bsum, int n) {
    __shared__ int s[256];
    int t = threadIdx.x, i = blockIdx.x * 256 + t;
    int v = (i < n) ? cnt[i] : 0;
    s[t] = v; __syncthreads();
    for (int o = 1; o < 256; o <<= 1) {
        int add = (t >= o) ? s[t - o] : 0;
        __syncthreads();
        s[t] += add;
        __syncthreads();
    }
    if (i < n) ofs[i] = s[t] - v;
    if (t == 255) bsum[blockIdx.x] = s[255];
}
__global__ void __launch_bounds__(256) k_scan_bsum(int* __restrict__ bsum, int nb) {
    __shared__ int s[256];
    __shared__ int run;
    int t = threadIdx.x;
    if (t == 0) run = 0;
    __syncthreads();
    for (int base = 0; base < nb; base += 256) {
        int i = base + t;
        int v = (i < nb) ? bsum[i] : 0;
        s[t] = v; __syncthreads();
        for (int o = 1; o < 256; o <<= 1) {
            int add = (t >= o) ? s[t - o] : 0;
            __syncthreads();
            s[t] += add;
            __syncthreads();
        }
        if (i < nb) bsum[i] = run + s[t] - v;
        __syncthreads();
        if (t == 0) run += s[255];
        __syncthreads();
    }
}
// finalizes ofs (adds block sums), copies cursor, writes sentinel ofs[n]=total
__global__ void __launch_bounds__(256) k_scan_add2(int* __restrict__ ofs, const int* __restrict__ bsum,
                                                   int* __restrict__ cursor, int n, int total) {
    int i = blockIdx.x * 256 + threadIdx.x;
    if (i < n) { int v = ofs[i] + bsum[blockIdx.x]; ofs[i] = v; cursor[i] = v; }
    if (i == 0) ofs[n] = total;
}
// line graph: permuted src + original->slot map (for angle encoder)
__global__ void __launch_bounds__(256) k_scatter_line2(
    const int* __restrict__ src, const int* __restrict__ dst, int* __restrict__ cur,
    int* __restrict__ srcP, int* __restrict__ pos, int E, int n)
{
    int i = blockIdx.x * 256 + threadIdx.x;
    if (i >= E) return;
    int d = clampi(dst[i], 0, n - 1);
    int s = clampi(src[i], 0, n - 1);
    int p = clampi(atomicAdd(&cur[d], 1), 0, E - 1);
    srcP[p] = s; pos[i] = p;
}
// atom graph: permuted src + original bond id per slot
__global__ void __launch_bounds__(256) k_scatter_atom2(
    const int* __restrict__ src, const int* __restrict__ dst, int* __restrict__ cur,
    int* __restrict__ srcP, int* __restrict__ eidP, int E, int n, int ns)
{
    int i = blockIdx.x * 256 + threadIdx.x;
    if (i >= E) return;
    int d = clampi(dst[i], 0, n - 1);
    int s = clampi(src[i], 0, ns - 1);
    int p = clampi(atomicAdd(&cur[d], 1), 0, E - 1);
    srcP[p] = s; eidP[p] = i;
}
// per-block-boundary node ranges (CSR static across rounds -> compute once)
// owner[b] = last d with ofs[d] <= b*FMAIN ; first[b] = first d with ofs[d] >= b*FMAIN
__global__ void __launch_bounds__(256) k_blkrange(const int* __restrict__ ofs, int N, int nbp1,
                                                  int* __restrict__ owner, int* __restrict__ first) {
    int b = blockIdx.x * 256 + threadIdx.x;
    if (b >= nbp1) return;
    int B0 = b * FMAIN;
    int lo = 0, hi = N;
    while (lo < hi) { int m = (lo + hi) >> 1; if (ofs[m] < B0) lo = m + 1; else hi = m; }
    first[b] = lo;
    lo = 0; hi = N + 1;
    while (lo < hi) { int m = (lo + hi) >> 1; if (ofs[m] <= B0) lo = m + 1; else hi = m; }
    owner[b] = (lo - 1) < 0 ? 0 : (lo - 1);
}

// ---------- encoders ----------
__global__ void __launch_bounds__(256) k_enc_atm(
    const int* __restrict__ sp_in,
    const void* W1, const void* b1, const void* W2, const void* b2,
    const void* g, const void* be, const int* __restrict__ flags,
    float* __restrict__ out)
{
    __shared__ float sW1[256], sW2[256], sb1[16], sb2[16], sg[16], sbe[16];
    int t = threadIdx.x, isbf = flags[0];
    sW1[t] = loadF(W1, t, isbf); sW2[t] = loadF(W2, t, isbf);
    if (t < 16) { sb1[t]=loadF(b1,t,isbf); sb2[t]=loadF(b2,t,isbf); sg[t]=loadF(g,t,isbf); sbe[t]=loadF(be,t,isbf); }
    __syncthreads();
    int i = blockIdx.x * 256 + t;
    if (i >= N_ATM) return;
    int sp = clampi(sp_in[i], 0, 15);
    float h[16];
#pragma unroll
    for (int j = 0; j < 16; j++) h[j] = siluf_(sW1[sp * 16 + j] + sb1[j]);
    float o[16]; float mu = 0.f;
#pragma unroll
    for (int j = 0; j < 16; j++) {
        float a = sb2[j];
#pragma unroll
        for (int k = 0; k < 16; k++) a += h[k] * sW2[k * 16 + j];
        o[j] = a; mu += a;
    }
    mu *= (1.f / 16.f);
    float var = 0.f;
#pragma unroll
    for (int j = 0; j < 16; j++) { float d = o[j] - mu; var += d * d; }
    var *= (1.f / 16.f);
    float r = rsqrtf(var + 1e-5f);
    float ov[16];
#pragma unroll
    for (int j = 0; j < 16; j++) ov[j] = (o[j] - mu) * r * sg[j] + sbe[j];
    store16f(out + (long long)i * 16, ov);
}

__global__ void __launch_bounds__(256) k_enc_bnd(
    const void* __restrict__ xb,
    const void* W1, const void* b1, const void* W2, const void* b2,
    const void* g, const void* be, const int* __restrict__ flags,
    bf16* __restrict__ out)
{
    __shared__ float sW1[256], sW2[256], sb1[16], sb2[16], sg[16], sbe[16];
    int t = threadIdx.x, isbf = flags[0];
    sW1[t] = loadF(W1, 256 + t, isbf); sW2[t] = loadF(W2, 256 + t, isbf);
    if (t < 16) { sb1[t]=loadF(b1,16+t,isbf); sb2[t]=loadF(b2,16+t,isbf); sg[t]=loadF(g,16+t,isbf); sbe[t]=loadF(be,16+t,isbf); }
    __syncthreads();
    int i = blockIdx.x * 256 + t;
    if (i >= N_BND) return;
    float x = loadF(xb, i, isbf) + 1e-5f;
    const float c = 0.6324555320336759f; // sqrt(2/5)
    float inv = c / x;
    float feat[16];
#pragma unroll
    for (int k = 0; k < 16; k++) feat[k] = __sinf((float)(k + 1) * PI_F * x * 0.2f) * inv;
    float h[16];
#pragma unroll
    for (int j = 0; j < 16; j++) {
        float a = sb1[j];
#pragma unroll
        for (int k = 0; k < 16; k++) a += feat[k] * sW1[k * 16 + j];
        h[j] = siluf_(a);
    }
    float o[16]; float mu = 0.f;
#pragma unroll
    for (int j = 0; j < 16; j++) {
        float a = sb2[j];
#pragma unroll
        for (int k = 0; k < 16; k++) a += h[k] * sW2[k * 16 + j];
        o[j] = a; mu += a;
    }
    mu *= (1.f / 16.f);
    float var = 0.f;
#pragma unroll
    for (int j = 0; j < 16; j++) { float d = o[j] - mu; var += d * d; }
    var *= (1.f / 16.f);
    float r = rsqrtf(var + 1e-5f);
    float ov[16];
#pragma unroll
    for (int j = 0; j < 16; j++) ov[j] = (o[j] - mu) * r * sg[j] + sbe[j];
    store16b(out + (long long)i * 16, ov);
}

// angle encoder: writes row to CSR slot pos[i]
__global__ void __launch_bounds__(256) k_enc_ang(
    const void* __restrict__ xa, const void* __restrict__ mask,
    const void* W1, const void* b1, const void* W2, const void* b2,
    const void* g, const void* be, const int* __restrict__ flags,
    const int* __restrict__ pos, bf16* __restrict__ out)
{
    __shared__ float sW1[512], sW2[512], sb1[32], sb2[32], sg[32], sbe[32];
    int t = threadIdx.x, isbf = flags[0], mbyte = flags[1];
    for (int i = t; i < 512; i += 256) { sW1[i] = loadF(W1, 512 + i, isbf); sW2[i] = loadF(W2, 512 + i, isbf); }
    if (t < 32) { sb1[t]=loadF(b1,32+t,isbf); sb2[t]=loadF(b2,32+t,isbf); sg[t]=loadF(g,32+t,isbf); sbe[t]=loadF(be,32+t,isbf); }
    __syncthreads();
    int i = blockIdx.x * 256 + t;
    if (i >= N_ANG) return;
    int m = mbyte ? (((const unsigned char*)mask)[i] != 0) : (((const int*)mask)[i] != 0);
    float x = loadF(xa, i, isbf);
    float gam = m ? 2.3873241463784303f : 4.7746482927568605f;   // 15/(2pi) : 15/pi
    float c0  = m ? -PI_F : 0.0f;
    float dc  = m ? 0.41887902047863906f : 0.20943951023931953f; // 2pi/15 : pi/15
    int wo = m * 256, vo = m * 16;
    float feat[16];
#pragma unroll
    for (int k = 0; k < 16; k++) {
        float d = gam * (x - (c0 + (float)k * dc));
        feat[k] = __expf(-d * d);
    }
    float h[16];
#pragma unroll
    for (int j = 0; j < 16; j++) {
        float a = sb1[vo + j];
#pragma unroll
        for (int k = 0; k < 16; k++) a += feat[k] * sW1[wo + k * 16 + j];
        h[j] = siluf_(a);
    }
    float o[16]; float mu = 0.f;
#pragma unroll
    for (int j = 0; j < 16; j++) {
        float a = sb2[vo + j];
#pragma unroll
        for (int k = 0; k < 16; k++) a += h[k] * sW2[wo + k * 16 + j];
        o[j] = a; mu += a;
    }
    mu *= (1.f / 16.f);
    float var = 0.f;
#pragma unroll
    for (int j = 0; j < 16; j++) { float d = o[j] - mu; var += d * d; }
    var *= (1.f / 16.f);
    float r = rsqrtf(var + 1e-5f);
    float ov[16];
#pragma unroll
    for (int j = 0; j < 16; j++) ov[j] = (o[j] - mu) * r * sg[vo + j] + sbe[vo + j];
    store16b(out + (long long)clampi(pos[i], 0, N_ANG - 1) * 16, ov);
}

// ---------- fused edge+node conv ----------
// Block b owns CSR slots [b*192, b*192+192); 256 threads (4 waves) cover main +
// <=64 extension slots (straddler node's tail; no Eout write there).
// LATENCY-ORIENTED edge phase (R7 post-mortem: 2 waves/SIMD + 3 serial gather
// chains = latency-bound at 8% VALU efficiency):
//  - all three row loads issued as RAW stages up front (one exposed round-trip),
//  - mm packed to LDS immediately after its matmul (16-reg live range dies early;
//    sigma stored separately, node phase computes num += sigma*mm in f32 from the
//    two bf16 values - same error class as bf16(sigma*mm), absmax budget holds),
//  - goal: demand <= 170 VGPR so the allocator lands 3 waves/SIMD on its own
//    (explicit caps backfired in R3/R4/R5 - stay demand-driven).
// Slot LDS layout (stride 5 uint4): [0..1]=mm (16 bf16), [2..3]=sigma (16 bf16).
// e fully ping-ponged (Ein read-only) so extension reads never race e_new writes.
// VIA_EID: e rows accessed through eid[] (atom graph: bonds in natural order).
// Node phase: all d with ofs[d] in [B0, B0+192); last block absorbs tail + deg-0
// nodes (num=den=0 -> matches reference). Tail blocks: mainLen = min(FMAIN, E-B0).
template <typename TX, bool VIA_EID>
__global__ void __launch_bounds__(NTHR) k_fused(
    const TX* __restrict__ X, TX* __restrict__ Xn,
    const bf16* __restrict__ Ein, bf16* __restrict__ Eout,
    const int* __restrict__ src, const int* __restrict__ eid,
    const int* __restrict__ ofs, const int* __restrict__ owner, const int* __restrict__ first,
    const float* __restrict__ W, const float* __restrict__ Bp, const float* __restrict__ L,
    int E, int N, int nb)
{
    __shared__ float sW[1280], sB[32], sLg[32], sLb[32];
    __shared__ uint4 sMS4[FWIN * 5];   // slot w -> sMS4[w*5 .. w*5+3], +1 pad
    __shared__ int sDst[FWIN];
    int t = threadIdx.x;
    int b = blockIdx.x;
    int B0 = b * FMAIN;
    for (int i = t; i < 1280; i += NTHR) sW[i] = W[i];
    if (t < 16) {
        sB[t] = Bp[t];        sB[16 + t] = Bp[16 + t];
        sLg[t] = L[32 + t];   sLb[t] = L[48 + t];       // edge LN
        sLg[16 + t] = L[t];   sLb[16 + t] = L[16 + t];  // node LN
    }
    int d0      = owner[b];
    int dNodeLo = first[b];
    int dhi     = first[b + 1];
    int dhiN    = (b == nb - 1) ? N : dhi;
    // fill slot -> dst map for the window
    for (int dd = d0 + t; dd < dhi; dd += NTHR) {
        int a = ofs[dd], e2 = ofs[dd + 1];
        int lo2 = a < B0 ? B0 : a;
        int hi2 = e2 > B0 + FWIN ? B0 + FWIN : e2;
        for (int p = lo2; p < hi2; p++) sDst[p - B0] = dd;
    }
    __syncthreads();
    // ---- edge phase ----
    int mainLen = E - B0; if (mainLen > FMAIN) mainLen = FMAIN;   // >0 always
    int eExt = ofs[clampi(dhi, 0, N)] - (B0 + FMAIN);
    eExt = eExt < 0 ? 0 : (eExt > FEXT ? FEXT : eExt);            // 0 for tail blocks
    bool act = (t < FMAIN) ? (t < mainLen) : (t < FMAIN + eExt);
    if (act) {
        int p = B0 + t;
        long long erow = VIA_EID ? (long long)clampi(eid[p], 0, E - 1) : (long long)p;
        // issue ALL THREE row loads together (concurrent round-trips in flight)
        Stage<TX> sxs, sxd;
        Stage<bf16> sev;
        { int s = clampi(src[p], 0, N - 1); sxs.issue(X + (long long)s * 16); }
        { int d = clampi(sDst[t], 0, N - 1); sxd.issue(X + (long long)d * 16); }
        sev.issue(Ein + erow * 16);
        float z[16];
        // consume xs: mm -> LDS (mm dies immediately), then z
        {
            float xs[16]; sxs.unpack(xs);
            {
                float mm[16];
#pragma unroll
                for (int j = 0; j < 16; j++) mm[j] = 0.f;
#pragma unroll
                for (int k = 0; k < 16; k++) {
                    float a = xs[k];
#pragma unroll
                    for (int j = 0; j < 16; j++) mm[j] += a * sW[1024 + k * 16 + j];
                }
                unsigned pm[8];
#pragma unroll
                for (int i = 0; i < 8; i++)
                    pm[i] = f2bfbits(mm[2*i]) | (f2bfbits(mm[2*i+1]) << 16);
                sMS4[t * 5 + 0] = make_uint4(pm[0], pm[1], pm[2], pm[3]);
                sMS4[t * 5 + 1] = make_uint4(pm[4], pm[5], pm[6], pm[7]);
            }
#pragma unroll
            for (int j = 0; j < 16; j++) z[j] = sB[j];
#pragma unroll
            for (int k = 0; k < 16; k++) {
                float a = xs[k];
#pragma unroll
                for (int j = 0; j < 16; j++) z[j] += a * sW[k * 16 + j];
            }
        }
        // consume xd -> z
        {
            float xd[16]; sxd.unpack(xd);
#pragma unroll
            for (int k = 0; k < 16; k++) {
                float a = xd[k];
#pragma unroll
                for (int j = 0; j < 16; j++) z[j] += a * sW[256 + k * 16 + j];
            }
        }
        // consume ev -> z (ev stays live for the residual)
        float ev[16]; sev.unpack(ev);
#pragma unroll
        for (int k = 0; k < 16; k++) {
            float a = ev[k];
#pragma unroll
            for (int j = 0; j < 16; j++) z[j] += a * sW[512 + k * 16 + j];
        }
        // sigma -> LDS
        {
            unsigned ps[8];
#pragma unroll
            for (int i = 0; i < 8; i++) {
                float a0 = sigmoidf_(z[2*i]);
                float a1 = sigmoidf_(z[2*i+1]);
                ps[i] = f2bfbits(a0) | (f2bfbits(a1) << 16);
            }
            sMS4[t * 5 + 2] = make_uint4(ps[0], ps[1], ps[2], ps[3]);
            sMS4[t * 5 + 3] = make_uint4(ps[4], ps[5], ps[6], ps[7]);
        }
        // LN + residual -> Eout (only main slots write)
        if (t < mainLen) {
            float mu = 0.f;
#pragma unroll
            for (int j = 0; j < 16; j++) mu += z[j];
            mu *= (1.f / 16.f);
            float var = 0.f;
#pragma unroll
            for (int j = 0; j < 16; j++) { float dd = z[j] - mu; var += dd * dd; }
            var *= (1.f / 16.f);
            float r = rsqrtf(var + 1e-5f);
            float eo[16];
#pragma unroll
            for (int j = 0; j < 16; j++)
                eo[j] = ev[j] + siluf_((z[j] - mu) * r * sLg[j] + sLb[j]);
            store16b(Eout + erow * 16, eo);
        }
    }
    __syncthreads();
    // ---- node phase (lean loop: only num/den live across the backedge) ----
    for (int d = dNodeLo + t; d < dhiN; d += NTHR) {
        float num[16], den[16];
#pragma unroll
        for (int j = 0; j < 16; j++) { num[j] = 0.f; den[j] = 0.f; }
        int p0 = ofs[d], p1 = ofs[d + 1];
        for (int p = p0; p < p1; p++) {
            int q5 = clampi(p - B0, 0, FWIN - 1) * 5;
            uint4 m0 = sMS4[q5 + 0], m1 = sMS4[q5 + 1];
            uint4 s0 = sMS4[q5 + 2], s1 = sMS4[q5 + 3];
            float sg;
            sg = bfbits2f(s0.x & 0xFFFFu); num[0]  += sg * bfbits2f(m0.x & 0xFFFFu); den[0]  += sg;
            sg = bfbits2f(s0.x >> 16);     num[1]  += sg * bfbits2f(m0.x >> 16);     den[1]  += sg;
            sg = bfbits2f(s0.y & 0xFFFFu); num[2]  += sg * bfbits2f(m0.y & 0xFFFFu); den[2]  += sg;
            sg = bfbits2f(s0.y >> 16);     num[3]  += sg * bfbits2f(m0.y >> 16);     den[3]  += sg;
            sg = bfbits2f(s0.z & 0xFFFFu); num[4]  += sg * bfbits2f(m0.z & 0xFFFFu); den[4]  += sg;
            sg = bfbits2f(s0.z >> 16);     num[5]  += sg * bfbits2f(m0.z >> 16);     den[5]  += sg;
            sg = bfbits2f(s0.w & 0xFFFFu); num[6]  += sg * bfbits2f(m0.w & 0xFFFFu); den[6]  += sg;
            sg = bfbits2f(s0.w >> 16);     num[7]  += sg * bfbits2f(m0.w >> 16);     den[7]  += sg;
            sg = bfbits2f(s1.x & 0xFFFFu); num[8]  += sg * bfbits2f(m1.x & 0xFFFFu); den[8]  += sg;
            sg = bfbits2f(s1.x >> 16);     num[9]  += sg * bfbits2f(m1.x >> 16);     den[9]  += sg;
            sg = bfbits2f(s1.y & 0xFFFFu); num[10] += sg * bfbits2f(m1.y & 0xFFFFu); den[10] += sg;
            sg = bfbits2f(s1.y >> 16);     num[11] += sg * bfbits2f(m1.y >> 16);     den[11] += sg;
            sg = bfbits2f(s1.z & 0xFFFFu); num[12] += sg * bfbits2f(m1.z & 0xFFFFu); den[12] += sg;
            sg = bfbits2f(s1.z >> 16);     num[13] += sg * bfbits2f(m1.z >> 16);     den[13] += sg;
            sg = bfbits2f(s1.w & 0xFFFFu); num[14] += sg * bfbits2f(m1.w & 0xFFFFu); den[14] += sg;
            sg = bfbits2f(s1.w >> 16);     num[15] += sg * bfbits2f(m1.w >> 16);     den[15] += sg;
        }
        // fold num/den, then bring in xv (NOT live during the loop above)
        float xv[16];
        loadRow<TX>(X + (long long)d * 16, xv);
        float tt[16]; float mu = 0.f;
#pragma unroll
        for (int j = 0; j < 16; j++) {
            float a = sB[16 + j] + num[j] / (den[j] + 1e-5f);
#pragma unroll
            for (int k = 0; k < 16; k++) a += xv[k] * sW[768 + k * 16 + j];
            tt[j] = a; mu += a;
        }
        mu *= (1.f / 16.f);
        float var = 0.f;
#pragma unroll
        for (int j = 0; j < 16; j++) { float dd2 = tt[j] - mu; var += dd2 * dd2; }
        var *= (1.f / 16.f);
        float r = rsqrtf(var + 1e-5f);
        float ov[16];
#pragma unroll
        for (int j = 0; j < 16; j++)
            ov[j] = xv[j] + siluf_((tt[j] - mu) * r * sLg[16 + j] + sLb[16 + j]);
        storeRow<TX>(Xn + (long long)d * 16, ov);
    }
}

// ---------- pooling: one block per graph (batch sorted, no atomics) ----------
__global__ void __launch_bounds__(256) k_pool2(
    const float* __restrict__ h, const int* __restrict__ batch, float* __restrict__ pooled)
{
    int g = blockIdx.x;
    int lo = 0, hi = N_ATM;
    while (lo < hi) { int m = (lo + hi) >> 1; if (batch[m] < g) lo = m + 1; else hi = m; }
    int s0 = lo;
    lo = 0; hi = N_ATM;
    while (lo < hi) { int m = (lo + hi) >> 1; if (batch[m] < g + 1) lo = m + 1; else hi = m; }
    int s1 = lo;
    float acc[16];
#pragma unroll
    for (int j = 0; j < 16; j++) acc[j] = 0.f;
    for (int i = s0 + threadIdx.x; i < s1; i += 256) {
        float v[16];
        load16f(h + (long long)i * 16, v);
#pragma unroll
        for (int j = 0; j < 16; j++) acc[j] += v[j];
    }
#pragma unroll
    for (int j = 0; j < 16; j++)
        for (int o = 32; o > 0; o >>= 1) acc[j] += __shfl_down(acc[j], o, 64);
    __shared__ float red[4][16];
    int wv = threadIdx.x >> 6, ln = threadIdx.x & 63;
    if (ln == 0)
#pragma unroll
        for (int j = 0; j < 16; j++) red[wv][j] = acc[j];
    __syncthreads();
    if (threadIdx.x < 16)
        pooled[g * 16 + threadIdx.x] = red[0][threadIdx.x] + red[1][threadIdx.x]
                                     + red[2][threadIdx.x] + red[3][threadIdx.x];
}

// ---------- head ----------
__global__ void __launch_bounds__(256) k_head(
    const float* __restrict__ pooled, const void* __restrict__ fp,
    const void* l1W, const void* l1b, const void* l2W, const void* l2b,
    const int* __restrict__ flags, void* __restrict__ out)
{
    __shared__ float sW[18 * 16], sb[16], s2W[16];
    int t = threadIdx.x, isbf = flags[0];
    for (int i = t; i < 288; i += 256) sW[i] = loadF(l1W, i, isbf);
    if (t < 16) { sb[t] = loadF(l1b, t, isbf); s2W[t] = loadF(l2W, t, isbf); }
    __syncthreads();
    int g = t;
    if (g >= N_GRAPHS) return;
    float in[18];
#pragma unroll
    for (int j = 0; j < 16; j++) in[j] = pooled[g * 16 + j];
    in[16] = loadF(fp, 2 * g, isbf);
    in[17] = loadF(fp, 2 * g + 1, isbf);
    float acc = loadF(l2b, 0, isbf);
#pragma unroll
    for (int j = 0; j < 16; j++) {
        float h = sb[j];
#pragma unroll
        for (int k = 0; k < 18; k++) h += in[k] * sW[k * 16 + j];
        h = (h > 0.f) ? h : 0.01f * h;
        acc += h * s2W[j];
    }
    if (isbf) ((bf16*)out)[g] = __float2bfloat16(acc);
    else      ((float*)out)[g] = acc;
}

extern "C" void kernel_launch(void* const* d_in, const int* in_sizes, int n_in,
                              void* d_out, int out_size, void* d_ws, size_t ws_size,
                              hipStream_t stream) {
    const int*  x_atm = (const int*)d_in[0];
    const void* x_bnd = d_in[1];
    const void* x_ang = d_in[2];
    const void* mask  = d_in[3];
    const int*  eiG   = (const int*)d_in[4];
    const int*  eiA   = (const int*)d_in[5];
    const int*  batch = (const int*)d_in[6];
    const void* fp    = d_in[7];
    const void* eW1 = d_in[8],  *eb1 = d_in[9],  *eW2 = d_in[10], *eb2 = d_in[11];
    const void* elg = d_in[12], *elb = d_in[13];
    const void* convW = d_in[14], *convB = d_in[15], *convLN = d_in[16];
    const void* l1W = d_in[17], *l1b = d_in[18], *l2W = d_in[19], *l2b = d_in[20];

    // Workspace layout — total ~239.8 MB (< proven-safe 241.2 MB)
    char* p = (char*)d_ws;
    int*   flags  = (int*)p;   p += 256;
    float* cw     = (float*)p; p += 7680 * 4;
    float* cb     = (float*)p; p += 192 * 4;
    float* cln    = (float*)p; p += 384 * 4;
    float* pooled = (float*)p; p += 4096 * 4;
    int*   bsum   = (int*)p;   p += 4096 * 4;
    int*   ownerL = (int*)p;   p += 11008 * 4;  // NB_L+1 = 10924 used
    int*   firstL = (int*)p;   p += 11008 * 4;
    int*   ownerA = (int*)p;   p += 5632 * 4;   // NB_A+1 = 5463 used
    int*   firstA = (int*)p;   p += 5632 * 4;
    int*   ofsB   = (int*)p;   p += (size_t)(N_BND + 256) * 4;  // +sentinel
    int*   srcB   = (int*)p;   p += (size_t)N_ANG * 4;
    int*   ofsA   = (int*)p;   p += (size_t)(N_ATM + 256) * 4;  // +sentinel
    int*   srcG   = (int*)p;   p += (size_t)N_BND * 4;
    int*   eidG   = (int*)p;   p += (size_t)N_BND * 4;
    float* atmA   = (float*)p; p += (size_t)N_ATM * 64;
    float* atmB   = (float*)p; p += (size_t)N_ATM * 64;
    bf16*  bndA   = (bf16*)p;  p += (size_t)N_BND * 32;
    bf16*  bndB   = (bf16*)p;  p += (size_t)N_BND * 32;
    bf16*  angA   = (bf16*)p;  p += (size_t)N_ANG * 32;
    bf16*  angB   = (bf16*)p;
    // overlay: cursors + angle slot map live in bndB, which is first written in
    // round-1 line node phase (long after CSR build + encoders are done)
    int*   curB   = (int*)bndB;          // N_BND ints (counts, then scatter cursor)
    int*   curA   = curB + N_BND;        // N_ATM ints
    int*   posB   = curA + N_ATM;        // N_ANG ints (angle -> slot, encoder only)

    // dtype detection + conv params
    k_zero_int<<<1, 64, 0, stream>>>(flags, 64);
    k_detect<<<512, 256, 0, stream>>>(elg, (const unsigned*)mask, flags);
    k_cvt_any<<<30, 256, 0, stream>>>(convW, cw, 7680, flags);
    k_cvt_any<<<1, 256, 0, stream>>>(convB, cb, 192, flags);
    k_cvt_any<<<2, 256, 0, stream>>>(convLN, cln, 384, flags);

    // CSR: line graph (bonds <- angle edges)
    k_zero_int<<<N_BND / 256, 256, 0, stream>>>(curB, N_BND);
    k_count<<<N_ANG / 256, 256, 0, stream>>>(eiA + N_ANG, curB, N_ANG, N_BND);
    k_scan_local<<<N_BND / 256, 256, 0, stream>>>(curB, ofsB, bsum, N_BND);
    k_scan_bsum<<<1, 256, 0, stream>>>(bsum, N_BND / 256);
    k_scan_add2<<<N_BND / 256, 256, 0, stream>>>(ofsB, bsum, curB, N_BND, N_ANG);
    k_scatter_line2<<<N_ANG / 256, 256, 0, stream>>>(eiA, eiA + N_ANG, curB, srcB, posB,
                                                     N_ANG, N_BND);
    k_blkrange<<<((NB_L + 1) + 255) / 256, 256, 0, stream>>>(ofsB, N_BND, NB_L + 1, ownerL, firstL);

    // CSR: atom graph (atoms <- bond edges)
    k_zero_int<<<N_ATM / 256, 256, 0, stream>>>(curA, N_ATM);
    k_count<<<N_BND / 256, 256, 0, stream>>>(eiG + N_BND, curA, N_BND, N_ATM);
    k_scan_local<<<N_ATM / 256, 256, 0, stream>>>(curA, ofsA, bsum, N_ATM);
    k_scan_bsum<<<1, 256, 0, stream>>>(bsum, N_ATM / 256);
    k_scan_add2<<<N_ATM / 256, 256, 0, stream>>>(ofsA, bsum, curA, N_ATM, N_BND);
    k_scatter_atom2<<<N_BND / 256, 256, 0, stream>>>(eiG, eiG + N_BND, curA, srcG, eidG,
                                                     N_BND, N_ATM, N_ATM);
    k_blkrange<<<((NB_A + 1) + 255) / 256, 256, 0, stream>>>(ofsA, N_ATM, NB_A + 1, ownerA, firstA);

    // encoders (k_enc_ang consumes posB; bndB overlay dies here)
    k_enc_atm<<<N_ATM / 256, 256, 0, stream>>>(x_atm, eW1, eb1, eW2, eb2, elg, elb, flags, atmA);
    k_enc_bnd<<<N_BND / 256, 256, 0, stream>>>(x_bnd, eW1, eb1, eW2, eb2, elg, elb, flags, bndA);
    k_enc_ang<<<N_ANG / 256, 256, 0, stream>>>(x_ang, mask, eW1, eb1, eW2, eb2, elg, elb, flags,
                                               posB, angA);

    // processor: per round, bonds go A->B (line) then B->A (atom): valid bonds
    // are always in bndA at round start. Angles and atoms ping-pong per round.
    float* atmCur = atmA; float* atmOth = atmB;
    bf16*  angCur = angA; bf16*  angOth = angB;
    for (int c = 0; c < 3; c++) {
        const float* Wl = cw + (size_t)(c * 2 + 0) * 1280;
        const float* Bl = cb + (size_t)(c * 2 + 0) * 32;
        const float* Ll = cln + (size_t)(c * 2 + 0) * 64;
        k_fused<bf16, false><<<NB_L, NTHR, 0, stream>>>(
            bndA, bndB, angCur, angOth, srcB, (const int*)nullptr,
            ofsB, ownerL, firstL, Wl, Bl, Ll, N_ANG, N_BND, NB_L);
        const float* Wa = cw + (size_t)(c * 2 + 1) * 1280;
        const float* Ba = cb + (size_t)(c * 2 + 1) * 32;
        const float* La = cln + (size_t)(c * 2 + 1) * 64;
        k_fused<float, true><<<NB_A, NTHR, 0, stream>>>(
            atmCur, atmOth, bndB, bndA, srcG, eidG,
            ofsA, ownerA, firstA, Wa, Ba, La, N_BND, N_ATM, NB_A);
        float* ft = atmCur; atmCur = atmOth; atmOth = ft;
        bf16*  bt = angCur; angCur = angOth; angOth = bt;
    }

    k_pool2<<<N_GRAPHS, 256, 0, stream>>>(atmCur, batch, pooled);
    k_head<<<1, 256, 0, stream>>>(pooled, fp, l1W, l1b, l2W, l2b, flags, d_out);
}